// Round 9
// baseline (1683.497 us; speedup 1.0000x reference)
//
#include <hip/hip_runtime.h>

typedef unsigned int u32;
typedef unsigned short u16;

constexpr int Gn  = 5000;
constexpr int Bn  = 32;
constexpr int Pn  = 5000;
constexpr int Nn  = Bn * Gn;  // 160000
constexpr int ECO = 1600000;
constexpr int EGG = 100000;
constexpr int NT64 = Nn / 64; // 2500

// ---- workspace layout (float offsets) ----
constexpr int oS1 = 0, oS2 = 128, oS4 = 384, oS5 = 640, oSG = 768, oSP1 = 896, oSP2 = 1024;
constexpr int oZERO = 1536;              // 64 zeros (t1 bias)
constexpr int oDONE = 1600;              // 8 int done-counters (zeroed)
constexpr int oA1 = 2048, oB1 = 2112, oA2 = 2176, oB2 = 2240;
constexpr int oA4 = 2304, oB4 = 2432;    // 128 each
constexpr int oA5 = 2560, oB5 = 2624;
constexpr int oAG = 2688, oBG = 2752;
constexpr int oAP1 = 2816, oBP1 = 2880;
constexpr int oAvec = 3072, oCvec = 3136, oCcP = 3200;
constexpr int oM  = 4096, oM1 = 8192, oM2 = 12288;
constexpr int oE2 = 16384, oCG2 = 22528;
constexpr int oTB  = 24576;              // 2048 floats (zeroed)
constexpr int oRG  = oTB + 2048;
constexpr int oRP  = oRG  + Gn * 64;     // pos renorm; becomes QBF after gather
constexpr int oRGO = oRP  + Gn * 64;
constexpr int oRBG = oRGO + Pn * 64;
constexpr int oAGO = oRBG + Pn * 64;
constexpr int oABG = oAGO + Pn * 64;
constexpr int oM1B = oABG + Pn * 64;
constexpr int oM2B = oM1B + Pn * 64;
constexpr int oDGO = oM2B + Pn * 64;
constexpr int oDBG = oDGO + Pn;
constexpr int oDEG = oDBG + Pn;
constexpr int oW1  = oDEG + Nn;
constexpr int oMBF   = oW1 + Nn;         // 4096 u16
constexpr int oW11BF = oMBF + 2048;
constexpr int oW1BF  = oW11BF + 2048;    // 8192 u16
constexpr int oW2BF  = oW1BF + 4096;
constexpr int oPAR   = oW2BF + 4096;     // kcg1s partials: 79 x 2048
constexpr int oBUF0 = oPAR + 79 * 2048;
constexpr int oBUF1 = oBUF0 + Nn * 64;
constexpr size_t WS_FLOATS = (size_t)oBUF1 + (size_t)Nn * 64;

__device__ inline u16 f2bf(float f) {
  u32 u = __float_as_uint(f);
  u = (u + 0x7fffu + ((u >> 16) & 1u)) >> 16;
  return (u16)u;
}
__device__ inline float bflo(u32 v) { return __uint_as_float(v << 16); }
__device__ inline float bfhi(u32 v) { return __uint_as_float(v & 0xffff0000u); }

typedef short s16x8 __attribute__((ext_vector_type(8)));
typedef float f32x4 __attribute__((ext_vector_type(4)));
union U4S8 { uint4 u; s16x8 s; };

// ---- merged zero: W[0:2048], Tb[2048], co_cnt[160001], go_cnt[5001], bg_cnt[5001] ----
__global__ __launch_bounds__(256) void kzero_all(float* W, float* tb, float* coc, float* goc, float* bgc) {
  int i = blockIdx.x * 256 + threadIdx.x;
  if (i < 2048) W[i] = 0.f;
  else if (i < 4096) tb[i - 2048] = 0.f;
  else if (i < 164097) coc[i - 4096] = 0.f;
  else if (i < 169098) goc[i - 164097] = 0.f;
  else if (i < 174099) bgc[i - 169098] = 0.f;
}

// ---- merged histogram (3 graphs) ----
__global__ __launch_bounds__(256) void khist3(const int* __restrict__ dco, int* __restrict__ cco, int* __restrict__ tco,
                                              const int* __restrict__ dgo, int* __restrict__ cgo, int* __restrict__ tgo,
                                              const int* __restrict__ dbg, int* __restrict__ cbg, int* __restrict__ tbg) {
  int b = blockIdx.x, t = threadIdx.x;
  if (b < 6250) { int e = b * 256 + t; if (e < ECO) tco[e] = atomicAdd(&cco[dco[e]], 1); }
  else if (b < 6641) { int e = (b - 6250) * 256 + t; if (e < EGG) tgo[e] = atomicAdd(&cgo[dgo[e]], 1); }
  else { int e = (b - 6641) * 256 + t; if (e < EGG) tbg[e] = atomicAdd(&cbg[dbg[e]], 1); }
}

// ---- merged scans ----
__global__ __launch_bounds__(256) void kscan1_3(const int* __restrict__ cco, const int* __restrict__ cgo,
                                                const int* __restrict__ cbg, int* __restrict__ bco,
                                                int* __restrict__ bgo, int* __restrict__ bbg) {
  __shared__ int sh[256];
  int b = blockIdx.x, t = threadIdx.x;
  const int* cnt; int* bsum; int n, lb;
  if (b < 157) { cnt = cco; bsum = bco; n = Nn; lb = b; }
  else if (b < 162) { cnt = cgo; bsum = bgo; n = Pn; lb = b - 157; }
  else { cnt = cbg; bsum = bbg; n = Pn; lb = b - 162; }
  int base = lb * 1024 + t * 4;
  int s = 0;
#pragma unroll
  for (int j = 0; j < 4; j++) { int i = base + j; if (i < n) s += cnt[i]; }
  sh[t] = s; __syncthreads();
  for (int d = 128; d; d >>= 1) { if (t < d) sh[t] += sh[t + d]; __syncthreads(); }
  if (t == 0) bsum[lb] = sh[0];
}
__global__ __launch_bounds__(256) void kscan2_3(int* bco, int* bgo, int* bbg,
                                                int* offco, int* offgo, int* offbg) {
  __shared__ int sh[256];
  int b = blockIdx.x, t = threadIdx.x;
  int* bsum; int nb; int* off_n;
  if (b == 0) { bsum = bco; nb = 157; off_n = offco; }
  else if (b == 1) { bsum = bgo; nb = 5; off_n = offgo; }
  else { bsum = bbg; nb = 5; off_n = offbg; }
  int v = (t < nb) ? bsum[t] : 0;
  sh[t] = v;
  __syncthreads();
  for (int d = 1; d < 256; d <<= 1) {
    int u = (t >= d) ? sh[t - d] : 0;
    __syncthreads();
    sh[t] += u;
    __syncthreads();
  }
  if (t < nb) bsum[t] = sh[t] - v;
  if (t == nb - 1) *off_n = sh[t];
}
__global__ __launch_bounds__(256) void kscan3_3(int* __restrict__ cco, int* __restrict__ cgo, int* __restrict__ cbg,
                                                const int* __restrict__ bco, const int* __restrict__ bgo,
                                                const int* __restrict__ bbg) {
  __shared__ int sh[256];
  int b = blockIdx.x, t = threadIdx.x;
  int* cnt; const int* bsum; int n, lb;
  if (b < 157) { cnt = cco; bsum = bco; n = Nn; lb = b; }
  else if (b < 162) { cnt = cgo; bsum = bgo; n = Pn; lb = b - 157; }
  else { cnt = cbg; bsum = bbg; n = Pn; lb = b - 162; }
  int base = lb * 1024 + t * 4;
  int c0 = (base + 0 < n) ? cnt[base + 0] : 0;
  int c1 = (base + 1 < n) ? cnt[base + 1] : 0;
  int c2 = (base + 2 < n) ? cnt[base + 2] : 0;
  int c3 = (base + 3 < n) ? cnt[base + 3] : 0;
  int tot = c0 + c1 + c2 + c3;
  sh[t] = tot; __syncthreads();
  for (int d = 1; d < 256; d <<= 1) {
    int v = (t >= d) ? sh[t - d] : 0;
    __syncthreads();
    sh[t] += v;
    __syncthreads();
  }
  int excl = sh[t] - tot + bsum[lb];
  if (base + 0 < n) cnt[base + 0] = excl;
  if (base + 1 < n) cnt[base + 1] = excl + c0;
  if (base + 2 < n) cnt[base + 2] = excl + c0 + c1;
  if (base + 3 < n) cnt[base + 3] = excl + c0 + c1 + c2;
}

// ---- merged CSR fill ----
__global__ __launch_bounds__(256) void kfillt3(
    const int* __restrict__ sco, const int* __restrict__ dco, const float* __restrict__ wco,
    const int* __restrict__ oco, const int* __restrict__ tco, float2* __restrict__ pco,
    const int* __restrict__ sgo, const int* __restrict__ dgo, const float* __restrict__ wgo,
    const int* __restrict__ ogo, const int* __restrict__ tgo, float2* __restrict__ pgo,
    const int* __restrict__ sbg, const int* __restrict__ dbg, const float* __restrict__ wbg,
    const int* __restrict__ obg, const int* __restrict__ tbg, float2* __restrict__ pbg) {
  int b = blockIdx.x, t = threadIdx.x;
  if (b < 6250) {
    int e = b * 256 + t;
    if (e < ECO) { int d = dco[e]; pco[oco[d] + tco[e]] = make_float2(wco[e], __int_as_float(sco[e])); }
  } else if (b < 6641) {
    int e = (b - 6250) * 256 + t;
    if (e < EGG) { int d = dgo[e]; pgo[ogo[d] + tgo[e]] = make_float2(wgo[e], __int_as_float(sgo[e])); }
  } else {
    int e = (b - 6641) * 256 + t;
    if (e < EGG) { int d = dbg[e]; pbg[obg[d] + tbg[e]] = make_float2(wbg[e], __int_as_float(sbg[e])); }
  }
}

// ---- merged dinv-from-row ----
__global__ __launch_bounds__(256) void kdinvrow3(const int* __restrict__ oco, const float2* __restrict__ pco,
                                                 float* __restrict__ dco,
                                                 const int* __restrict__ ogo, const float2* __restrict__ pgo,
                                                 float* __restrict__ dgo,
                                                 const int* __restrict__ obg, const float2* __restrict__ pbg,
                                                 float* __restrict__ dbg) {
  int b = blockIdx.x, t = threadIdx.x;
  const int* off; const float2* pack; float* dinv; int n, i;
  if (b < 625) { off = oco; pack = pco; dinv = dco; n = Nn; i = b * 256 + t; }
  else if (b < 645) { off = ogo; pack = pgo; dinv = dgo; n = Pn; i = (b - 625) * 256 + t; }
  else { off = obg; pack = pbg; dinv = dbg; n = Pn; i = (b - 645) * 256 + t; }
  if (i >= n) return;
  int b0 = off[i], b1 = off[i + 1];
  float s = 1.f;
  for (int j = b0; j < b1; j++) s += pack[j].x;
  dinv[i] = rsqrtf(s);
}

// ---- merged renorm (4 tables; gene with stats) ----
__global__ __launch_bounds__(256) void krenorm4(const float* __restrict__ gene, float* __restrict__ rg,
                                                float* __restrict__ sg,
                                                const float* __restrict__ pos, float* __restrict__ rp,
                                                const float* __restrict__ got, float* __restrict__ rgo,
                                                const float* __restrict__ bgt, float* __restrict__ rbg) {
  int b = blockIdx.x;
  const float* in; float* out; float* stats = nullptr; int rows, lb;
  if (b < 160) { in = gene; out = rg; stats = sg; rows = Gn; lb = b; }
  else if (b < 320) { in = pos; out = rp; rows = Gn; lb = b - 160; }
  else if (b < 480) { in = got; out = rgo; rows = Pn; lb = b - 320; }
  else { in = bgt; out = rbg; rows = Pn; lb = b - 480; }
  int lane = threadIdx.x & 63, wv = threadIdx.x >> 6;
  int gw = lb * 4 + wv, nw = 160 * 4;
  float ps = 0.f, pq = 0.f;
  for (int r = gw; r < rows; r += nw) {
    float v = in[r * 64 + lane];
    float sq = v * v;
    for (int off = 32; off; off >>= 1) sq += __shfl_xor(sq, off, 64);
    float s = fminf(1.f, 1.f / fmaxf(sqrtf(sq), 1e-12f));
    float o = v * s;
    out[r * 64 + lane] = o;
    ps += o; pq += o * o;
  }
  if (!stats) return;
  __shared__ float red[4][64], red2[4][64];
  red[wv][lane] = ps; red2[wv][lane] = pq;
  __syncthreads();
  if (wv == 0) {
    float s = red[0][lane] + red[1][lane] + red[2][lane] + red[3][lane];
    float q = red2[0][lane] + red2[1][lane] + red2[2][lane] + red2[3][lane];
    atomicAdd(&stats[lane], s);
    atomicAdd(&stats[64 + lane], q);
  }
}

// ---- merged gather (3 graphs; co -> bf16) ----
__global__ __launch_bounds__(256) void kgather3(
    const int* __restrict__ oco, const float2* __restrict__ pco, const float* __restrict__ dco,
    const float* __restrict__ tabco, u16* __restrict__ outco,
    const int* __restrict__ ogo, const float2* __restrict__ pgo, const float* __restrict__ dgo,
    const float* __restrict__ tabgo, float* __restrict__ outgo,
    const int* __restrict__ obg, const float2* __restrict__ pbg, const float* __restrict__ dbg,
    const float* __restrict__ tabbg, float* __restrict__ outbg) {
  int b = blockIdx.x;
  const int* off; const float2* pack; const float* dinv; const float* tab;
  u16* ob = nullptr; float* of = nullptr; int n, wv0, nw;
  if (b < 2048) { off = oco; pack = pco; dinv = dco; tab = tabco; ob = outco; n = Nn; wv0 = b * 4; nw = 2048 * 4; }
  else if (b < 2560) { off = ogo; pack = pgo; dinv = dgo; tab = tabgo; of = outgo; n = Pn; wv0 = (b - 2048) * 4; nw = 512 * 4; }
  else { off = obg; pack = pbg; dinv = dbg; tab = tabbg; of = outbg; n = Pn; wv0 = (b - 2560) * 4; nw = 512 * 4; }
  int lane = threadIdx.x & 63;
  for (int i = wv0 + (threadIdx.x >> 6); i < n; i += nw) {
    int b0 = off[i], b1 = off[i + 1];
    float di = dinv[i];
    float acc = di * tab[(i % Gn) * 64 + lane];
    for (int base = b0; base < b1; base += 64) {
      int m = b1 - base; if (m > 64) m = 64;
      float cj = 0.f; int idxj = 0;
      if (lane < m) {
        float2 p = pack[base + lane];
        int s = __float_as_int(p.y);
        cj = p.x * dinv[s];
        idxj = (s % Gn) * 64;
      }
      int j = 0;
      for (; j + 1 < m; j += 2) {
        float c0 = __shfl(cj, j, 64);     int i0 = __shfl(idxj, j, 64);
        float c1 = __shfl(cj, j + 1, 64); int i1 = __shfl(idxj, j + 1, 64);
        acc = fmaf(c0, tab[i0 + lane], acc);
        acc = fmaf(c1, tab[i1 + lane], acc);
      }
      if (j < m) {
        float c0 = __shfl(cj, j, 64); int i0 = __shfl(idxj, j, 64);
        acc = fmaf(c0, tab[i0 + lane], acc);
      }
    }
    acc *= di;
    if (ob) ob[(size_t)i * 64 + lane] = f2bf(acc);
    else of[(size_t)i * 64 + lane] = acc;
  }
}

// ---- smallmat as device fn ----
__device__ void smallmat_dev(const float* A, const float* Bm, float alpha, const float* bias,
                             const float* bv1, const float* bv2, float beta, float* Mout, float* cvec) {
  __shared__ float As[4096], Bs[4096];
  int t = threadIdx.x;
  for (int m = 0; m < 16; m++) { As[m * 256 + t] = A[m * 256 + t]; Bs[m * 256 + t] = Bm[m * 256 + t]; }
  __syncthreads();
  int j = t & 63, ig = t >> 6;
  for (int ii = 0; ii < 16; ii++) {
    int i = ig * 16 + ii;
    float acc = 0.f;
    for (int k = 0; k < 64; k++) acc += As[i * 64 + k] * Bs[k * 64 + j];
    Mout[i * 64 + j] = alpha * acc;
  }
  if (cvec && t < 64) {
    float acc = bias ? bias[t] : 0.f;
    for (int k = 0; k < 64; k++) {
      float bb = (bv1 ? bv1[k] : 0.f) + (bv2 ? bv2[k] : 0.f);
      acc += beta * As[t * 64 + k] * bb;
    }
    cvec[t] = acc;
  }
}

// ---- prep: 3 smallmats + kfin(SG) + bf16 weight converts ----
__global__ __launch_bounds__(256) void kprep(
    const float* __restrict__ mlpW, const float* __restrict__ mlpB,
    const float* __restrict__ sgW, const float* __restrict__ sgB,
    const float* __restrict__ SG, const float* __restrict__ bng, const float* __restrict__ bnb,
    float* __restrict__ M, float* __restrict__ Cvec, float* __restrict__ M1,
    float* __restrict__ M2, float* __restrict__ CcP,
    float* __restrict__ AG, float* __restrict__ BG,
    const float* __restrict__ recW1, const float* __restrict__ recW2,
    u16* __restrict__ W11bf, u16* __restrict__ W1bf, u16* __restrict__ W2bf) {
  int b = blockIdx.x, t = threadIdx.x;
  if (b == 0) smallmat_dev(mlpW + 8192, sgW, 0.2f, mlpB + 128, sgB, nullptr, 0.2f, M, Cvec);
  else if (b == 1) smallmat_dev(mlpW, sgW + 4096, 1.f, nullptr, nullptr, nullptr, 0.f, M1, nullptr);
  else if (b == 2) smallmat_dev(mlpW, sgW + 8192, 1.f, mlpB, sgB + 64, sgB + 128, 1.f, M2, CcP);
  else if (b == 3) {
    if (t < 64) {
      float mean = SG[t] / (float)Gn;
      float var = SG[64 + t] / (float)Gn - mean * mean;
      float sc = bng[t] * rsqrtf(var + 1e-5f);
      AG[t] = sc; BG[t] = bnb[t] - mean * sc;
    }
  } else if (b < 20) {
    int i = (b - 4) * 256 + t; if (i < 4096) W11bf[i] = f2bf(mlpW[12288 + i]);
  } else if (b < 52) {
    int i = (b - 20) * 256 + t; if (i < 8192) W1bf[i] = f2bf(recW1[i]);
  } else {
    int i = (b - 52) * 256 + t; if (i < 8192) W2bf[i] = f2bf(recW2[i]);
  }
}

// ---- Q gemm (bf16 out) + M convert ----
__global__ __launch_bounds__(256) void kqgemm(const float* __restrict__ RG, const float* __restrict__ AG,
                                              const float* __restrict__ BG, const float* __restrict__ W10,
                                              const float* __restrict__ Cvec, u16* __restrict__ QBF,
                                              const float* __restrict__ M, u16* __restrict__ Mbf) {
  int b = blockIdx.x, t = threadIdx.x;
  if (b >= 79) {
    int i = (b - 79) * 256 + t; if (i < 4096) Mbf[i] = f2bf(M[i]);
    return;
  }
  __shared__ float xs[4096];
  int lane = t & 63, wv = t >> 6;
  int base = b * 64;
#pragma unroll
  for (int m = 0; m < 16; m++) {
    int fl = m * 256 + t;
    int r = fl >> 6, c = fl & 63;
    int gr = base + r;
    float v = (gr < Gn) ? fmaxf(AG[c] * RG[gr * 64 + c] + BG[c], 0.f) : 0.f;
    xs[fl] = v;
  }
  __syncthreads();
  float Wreg[64];
#pragma unroll
  for (int k = 0; k < 64; k++) Wreg[k] = W10[lane * 64 + k];
  float bb = Cvec[lane];
#pragma unroll
  for (int j = 0; j < 16; j++) {
    int gr = base + wv * 16 + j;
    if (gr >= Gn) break;
    const float4* xr = (const float4*)&xs[(wv * 16 + j) * 64];
    float a = bb;
#pragma unroll
    for (int kk = 0; kk < 16; kk++) {
      float4 xv = xr[kk];
      a = fmaf(xv.x, Wreg[4 * kk + 0], a);
      a = fmaf(xv.y, Wreg[4 * kk + 1], a);
      a = fmaf(xv.z, Wreg[4 * kk + 2], a);
      a = fmaf(xv.w, Wreg[4 * kk + 3], a);
    }
    QBF[gr * 64 + lane] = f2bf(a);
  }
}

// ---- small fp32 GEMM (pert path) with optional in-kernel BN finalize ----
template <bool TWO, bool PRE, bool FIN>
__global__ __launch_bounds__(256) void gemm64k(
    const float* __restrict__ X, const float* __restrict__ Xb,
    const float* __restrict__ Wm, const float* __restrict__ Wb,
    const float* __restrict__ bias,
    const float* __restrict__ pa, const float* __restrict__ pb,
    float* __restrict__ Y, float* __restrict__ stats, int rows,
    int* done, const float* __restrict__ gv, const float* __restrict__ btv,
    float* __restrict__ aout, float* __restrict__ bout, float invn) {
  __shared__ float xs[4096];
  __shared__ float red[4][64], red2[4][64];
  __shared__ int lastf;
  int t = threadIdx.x, lane = t & 63, wv = t >> 6;
  int ntiles = (rows + 63) >> 6;
  float psum = 0.f, psq = 0.f;
  float bv = bias ? bias[lane] : 0.f;
  for (int tile = blockIdx.x; tile < ntiles; tile += gridDim.x) {
    int base = tile * 64;
    float acc[16];
#pragma unroll
    for (int j = 0; j < 16; j++) acc[j] = bv;
    for (int pass = 0; pass < (TWO ? 2 : 1); pass++) {
      const float* Xp = pass ? Xb : X;
      const float* Wp = pass ? Wb : Wm;
      __syncthreads();
#pragma unroll
      for (int m = 0; m < 16; m++) {
        int fl = m * 256 + t;
        int r = fl >> 6, c = fl & 63;
        int gr = base + r;
        float v = (gr < rows) ? Xp[gr * 64 + c] : 0.f;
        if (PRE) { v = fmaxf(pa[c] * v + pb[c], 0.f); }
        xs[fl] = v;
      }
      __syncthreads();
      float Wreg[64];
#pragma unroll
      for (int k = 0; k < 64; k++) Wreg[k] = Wp[lane * 64 + k];
#pragma unroll
      for (int j = 0; j < 16; j++) {
        const float4* xr = (const float4*)&xs[(wv * 16 + j) * 64];
        float a = acc[j];
#pragma unroll
        for (int kk = 0; kk < 16; kk++) {
          float4 xv = xr[kk];
          a = fmaf(xv.x, Wreg[4 * kk + 0], a);
          a = fmaf(xv.y, Wreg[4 * kk + 1], a);
          a = fmaf(xv.z, Wreg[4 * kk + 2], a);
          a = fmaf(xv.w, Wreg[4 * kk + 3], a);
        }
        acc[j] = a;
      }
    }
#pragma unroll
    for (int j = 0; j < 16; j++) {
      int gr = base + wv * 16 + j;
      if (gr < rows) {
        float v = acc[j];
        Y[gr * 64 + lane] = v;
        psum += v; psq += v * v;
      }
    }
  }
  __syncthreads();
  red[wv][lane] = psum; red2[wv][lane] = psq;
  __syncthreads();
  if (wv == 0) {
    float s = red[0][lane] + red[1][lane] + red[2][lane] + red[3][lane];
    float q = red2[0][lane] + red2[1][lane] + red2[2][lane] + red2[3][lane];
    atomicAdd(&stats[lane], s);
    atomicAdd(&stats[64 + lane], q);
  }
  if (FIN) {
    __threadfence();
    __syncthreads();
    if (t == 0) lastf = (atomicAdd(done, 1) == (int)gridDim.x - 1);
    __syncthreads();
    if (lastf && t < 64) {
      float s = atomicAdd(&stats[t], 0.f);
      float q = atomicAdd(&stats[64 + t], 0.f);
      float mean = s * invn, var = q * invn - mean * mean;
      float sc = gv[t] * rsqrtf(var + 1e-5f);
      aout[t] = sc; bout[t] = btv[t] - mean * sc;
    }
  }
}

// ---- MFMA bf16 GEMM, 64-row tiles, atomics stats + in-kernel finalize ----
template <int KH, int CTT, bool PRE, bool EB, bool PERG, bool TB, bool FIN>
__global__ __launch_bounds__(256, (CTT == 8 ? 4 : 6)) void gemm_mf64(
    const u16* __restrict__ Xb, const u16* __restrict__ Wb,
    const float* __restrict__ bias, const float* __restrict__ pa, const float* __restrict__ pb,
    const u16* __restrict__ qbf, u16* __restrict__ Ybf, int obpitch,
    float* __restrict__ stats, float* __restrict__ Tb,
    int* done, const float* __restrict__ gv, const float* __restrict__ btv,
    float* __restrict__ aout, float* __restrict__ bout, float invn) {
  constexpr int K = KH * 32;
  constexpr int NCOL = CTT * 16;
  constexpr int HALVES = CTT / 4;
  __shared__ float xs[64 * 68];
  __shared__ float sstat[2 * NCOL];
  __shared__ float tbs[128];
  __shared__ int lastf;
  int t = threadIdx.x;
  int w = t >> 6, lane = t & 63;
  int lr = lane & 15, lk = lane >> 4;
  int cg = t & 7, rg = t >> 3;
  int R0 = blockIdx.x * 64;
  int rowA = R0 + w * 16 + lr;
  int b0 = R0 / Gn;
  int bE = (R0 + 63) / Gn;
  float sS[HALVES][8], sQ[HALVES][8], tS[2][8];
#pragma unroll
  for (int h = 0; h < HALVES; h++)
#pragma unroll
    for (int j = 0; j < 8; j++) { sS[h][j] = 0.f; sQ[h][j] = 0.f; }
#pragma unroll
  for (int s = 0; s < 2; s++)
#pragma unroll
    for (int j = 0; j < 8; j++) tS[s][j] = 0.f;
  for (int idx = t; idx < 2 * NCOL; idx += 256) sstat[idx] = 0.f;
  if (TB) for (int idx = t; idx < 128; idx += 256) tbs[idx] = 0.f;

  f32x4 acc[CTT];
#pragma unroll
  for (int ct = 0; ct < CTT; ct++) acc[ct] = (f32x4){0.f, 0.f, 0.f, 0.f};
#pragma unroll
  for (int kh = 0; kh < KH; kh++) {
    int kb = kh * 32 + lk * 8;
    s16x8 af;
    if (PRE) {
      uint4 u = *(const uint4*)&Xb[(size_t)rowA * K + kb];
      float4 A0 = *(const float4*)&pa[kb];
      float4 A1 = *(const float4*)&pa[kb + 4];
      const float* pbb = EB ? &pb[(rowA / Gn) * 64] : pb;
      float4 B0 = *(const float4*)&pbb[kb];
      float4 B1 = *(const float4*)&pbb[kb + 4];
      float v0 = fmaxf(fmaf(A0.x, bflo(u.x), B0.x), 0.f);
      float v1 = fmaxf(fmaf(A0.y, bfhi(u.x), B0.y), 0.f);
      float v2 = fmaxf(fmaf(A0.z, bflo(u.y), B0.z), 0.f);
      float v3 = fmaxf(fmaf(A0.w, bfhi(u.y), B0.w), 0.f);
      float v4 = fmaxf(fmaf(A1.x, bflo(u.z), B1.x), 0.f);
      float v5 = fmaxf(fmaf(A1.y, bfhi(u.z), B1.y), 0.f);
      float v6 = fmaxf(fmaf(A1.z, bflo(u.w), B1.z), 0.f);
      float v7 = fmaxf(fmaf(A1.w, bfhi(u.w), B1.w), 0.f);
      U4S8 c;
      c.u.x = (u32)f2bf(v0) | ((u32)f2bf(v1) << 16);
      c.u.y = (u32)f2bf(v2) | ((u32)f2bf(v3) << 16);
      c.u.z = (u32)f2bf(v4) | ((u32)f2bf(v5) << 16);
      c.u.w = (u32)f2bf(v6) | ((u32)f2bf(v7) << 16);
      af = c.s;
    } else {
      af = *(const s16x8*)&Xb[(size_t)rowA * K + kb];
    }
#pragma unroll
    for (int ct = 0; ct < CTT; ct++) {
      s16x8 bfr = *(const s16x8*)&Wb[(ct * 16 + lr) * K + kb];
      acc[ct] = __builtin_amdgcn_mfma_f32_16x16x32_bf16(af, bfr, acc[ct], 0, 0, 0);
    }
  }
#pragma unroll
  for (int h = 0; h < HALVES; h++) {
    __syncthreads();
#pragma unroll
    for (int ct2 = 0; ct2 < 4; ct2++)
#pragma unroll
      for (int r = 0; r < 4; r++)
        xs[(w * 16 + lk * 4 + r) * 68 + ct2 * 16 + lr] = acc[h * 4 + ct2][r];
    __syncthreads();
    float4 bb0 = *(const float4*)&bias[h * 64 + cg * 8];
    float4 bb1 = *(const float4*)&bias[h * 64 + cg * 8 + 4];
#pragma unroll
    for (int i = 0; i < 2; i++) {
      int lrow = rg * 2 + i;
      int grow = R0 + lrow;
      float4 x0 = *(const float4*)&xs[lrow * 68 + cg * 8];
      float4 x1 = *(const float4*)&xs[lrow * 68 + cg * 8 + 4];
      float v[8] = {x0.x + bb0.x, x0.y + bb0.y, x0.z + bb0.z, x0.w + bb0.w,
                    x1.x + bb1.x, x1.y + bb1.y, x1.z + bb1.z, x1.w + bb1.w};
      if (PERG) {
        int qr = grow % Gn;
        uint4 q = *(const uint4*)&qbf[(size_t)qr * 64 + cg * 8];
        v[0] += bflo(q.x); v[1] += bfhi(q.x); v[2] += bflo(q.y); v[3] += bfhi(q.y);
        v[4] += bflo(q.z); v[5] += bfhi(q.z); v[6] += bflo(q.w); v[7] += bfhi(q.w);
      }
#pragma unroll
      for (int j = 0; j < 8; j++) { sS[h][j] += v[j]; sQ[h][j] += v[j] * v[j]; }
      if (TB) {
        int slot = (grow / Gn) != b0;
#pragma unroll
        for (int j = 0; j < 8; j++) tS[slot][j] += v[j];
      }
      uint4 o;
      o.x = (u32)f2bf(v[0]) | ((u32)f2bf(v[1]) << 16);
      o.y = (u32)f2bf(v[2]) | ((u32)f2bf(v[3]) << 16);
      o.z = (u32)f2bf(v[4]) | ((u32)f2bf(v[5]) << 16);
      o.w = (u32)f2bf(v[6]) | ((u32)f2bf(v[7]) << 16);
      *(uint4*)&Ybf[(size_t)grow * obpitch + h * 64 + cg * 8] = o;
    }
  }
  __syncthreads();
#pragma unroll
  for (int h = 0; h < HALVES; h++)
#pragma unroll
    for (int j = 0; j < 8; j++) {
      atomicAdd(&sstat[h * 64 + cg * 8 + j], sS[h][j]);
      atomicAdd(&sstat[NCOL + h * 64 + cg * 8 + j], sQ[h][j]);
    }
  if (TB) {
#pragma unroll
    for (int j = 0; j < 8; j++) {
      atomicAdd(&tbs[cg * 8 + j], tS[0][j]);
      atomicAdd(&tbs[64 + cg * 8 + j], tS[1][j]);
    }
  }
  __syncthreads();
  for (int idx = t; idx < 2 * NCOL; idx += 256) atomicAdd(&stats[idx], sstat[idx]);
  if (TB) {
    if (t < 64) atomicAdd(&Tb[b0 * 64 + t], tbs[t]);
    else if (t < 128 && bE != b0) atomicAdd(&Tb[bE * 64 + (t - 64)], tbs[t - 64]);
  }
  if (FIN) {
    __threadfence();
    __syncthreads();
    if (t == 0) lastf = (atomicAdd(done, 1) == (int)gridDim.x - 1);
    __syncthreads();
    if (lastf && t < NCOL) {
      float s = atomicAdd(&stats[t], 0.f);
      float q = atomicAdd(&stats[NCOL + t], 0.f);
      float mean = s * invn, var = q * invn - mean * mean;
      float sc = gv[t] * rsqrtf(var + 1e-5f);
      aout[t] = sc; bout[t] = btv[t] - mean * sc;
    }
  }
}

// ---- kembS3: finalize SP2 + pert-MLP (BN over 32) + analytic S3 -> Avec, e2 ----
__global__ __launch_bounds__(256) void kembS3(
    const float* __restrict__ SP2, const float* __restrict__ mg64, const float* __restrict__ mbt64,
    const float* __restrict__ m2, const int* __restrict__ pidx,
    const float* __restrict__ Wm, const float* __restrict__ bv,
    const float* __restrict__ gg, const float* __restrict__ btv,
    const float* __restrict__ S2, const float* __restrict__ a2, const float* __restrict__ b2,
    const float* __restrict__ Tb, const float* __restrict__ g3, const float* __restrict__ bt3,
    float* __restrict__ Avec, float* __restrict__ e2) {
  int t = threadIdx.x, c = t & 63, bg = t >> 6;
  __shared__ float xin[2048], hmid[2048], embs[2048], sred[4][64], qred[4][64], asc[64], bsh[64];
  __shared__ float aP2s[64], bP2s[64], a3s[64], b3s[64];
  if (t < 64) {
    float mean = SP2[t] / (float)Pn;
    float var = SP2[64 + t] / (float)Pn - mean * mean;
    float sc = mg64[t] * rsqrtf(var + 1e-5f);
    aP2s[t] = sc; bP2s[t] = mbt64[t] - mean * sc;
  }
  __syncthreads();
  for (int idx = t; idx < 2048; idx += 256) {
    int b = idx >> 6, cc = idx & 63;
    xin[idx] = aP2s[cc] * m2[pidx[b] * 64 + cc] + bP2s[cc];
  }
  __syncthreads();
  float y[8];
  float ps = 0.f, pq = 0.f;
  for (int jb = 0; jb < 8; jb++) {
    int b = bg * 8 + jb;
    float a = bv[c];
    for (int k = 0; k < 64; k++) a += xin[b * 64 + k] * Wm[c * 64 + k];
    y[jb] = a; ps += a; pq += a * a;
  }
  sred[bg][c] = ps; qred[bg][c] = pq;
  __syncthreads();
  if (t < 64) {
    float s = sred[0][t] + sred[1][t] + sred[2][t] + sred[3][t];
    float q = qred[0][t] + qred[1][t] + qred[2][t] + qred[3][t];
    float mean = s * (1.f / 32.f), var = q * (1.f / 32.f) - mean * mean;
    float sc = gg[t] * rsqrtf(var + 1e-5f);
    asc[t] = sc; bsh[t] = btv[t] - mean * sc;
  }
  __syncthreads();
  for (int jb = 0; jb < 8; jb++) { int b = bg * 8 + jb; hmid[b * 64 + c] = fmaxf(asc[c] * y[jb] + bsh[c], 0.f); }
  __syncthreads();
  ps = 0.f; pq = 0.f;
  for (int jb = 0; jb < 8; jb++) {
    int b = bg * 8 + jb;
    float a = bv[64 + c];
    for (int k = 0; k < 64; k++) a += hmid[b * 64 + k] * Wm[4096 + c * 64 + k];
    y[jb] = a; ps += a; pq += a * a;
  }
  sred[bg][c] = ps; qred[bg][c] = pq;
  __syncthreads();
  if (t < 64) {
    float s = sred[0][t] + sred[1][t] + sred[2][t] + sred[3][t];
    float q = qred[0][t] + qred[1][t] + qred[2][t] + qred[3][t];
    float mean = s * (1.f / 32.f), var = q * (1.f / 32.f) - mean * mean;
    float sc = gg[64 + t] * rsqrtf(var + 1e-5f);
    asc[t] = sc; bsh[t] = btv[64 + t] - mean * sc;
  }
  __syncthreads();
  for (int jb = 0; jb < 8; jb++) { int b = bg * 8 + jb; embs[b * 64 + c] = asc[c] * y[jb] + bsh[c]; }
  __syncthreads();
  if (t < 64) {
    float a2c = a2[t], b2c = b2[t];
    float se = 0.f, sct = 0.f, sc2 = 0.f;
    for (int b = 0; b < Bn; b++) {
      float cb = b2c + embs[b * 64 + t];
      se += cb;
      sct += cb * Tb[b * 64 + t];
      sc2 += cb * cb;
    }
    float sum_u = a2c * S2[t] + (float)Gn * se;
    float sq_u = a2c * a2c * S2[64 + t] + 2.f * a2c * sct + (float)Gn * sc2;
    float mean = sum_u / (float)Nn;
    float var = sq_u / (float)Nn - mean * mean;
    float sc = g3[t] * rsqrtf(var + 1e-5f);
    a3s[t] = sc; b3s[t] = bt3[t] - mean * sc;
    Avec[t] = sc * a2c;
  }
  __syncthreads();
  for (int idx = t; idx < 2048; idx += 256) {
    int cc = idx & 63;
    e2[idx] = a3s[cc] * (b2[cc] + embs[idx]) + b3s[cc];
  }
}

// ---- w1 per-gene dot ----
__global__ __launch_bounds__(256) void k13_kernel(const u16* __restrict__ R2, const float* __restrict__ a5,
                                                  const float* __restrict__ b5, const float* __restrict__ iw1,
                                                  const float* __restrict__ ib1, float* __restrict__ w1out,
                                                  int rows) {
  int t = blockIdx.x * 256 + threadIdx.x;
  int i = t >> 4, j = t & 15;
  if (i >= rows) return;
  int g = i % Gn;
  uint2 u = *(const uint2*)&R2[(size_t)i * 64 + j * 4];
  float rx = bflo(u.x), ry = bfhi(u.x), rz = bflo(u.y), rw = bfhi(u.y);
  float4 a = ((const float4*)a5)[j];
  float4 b = ((const float4*)b5)[j];
  float4 w = ((const float4*)iw1)[g * 16 + j];
  float p = (a.x * rx + b.x) * w.x + (a.y * ry + b.y) * w.y +
            (a.z * rz + b.z) * w.z + (a.w * rw + b.w) * w.w;
  for (int off = 8; off; off >>= 1) p += __shfl_xor(p, off, 64);
  if (j == 0) w1out[i] = p + ib1[g];
}

// ---- split-K cross-gene: partials (plain stores) ----
__global__ __launch_bounds__(256) void kcg1s(const float* __restrict__ w1, const float* __restrict__ cgW1,
                                             float* __restrict__ PAR) {
  __shared__ float w1s[64 * 36];
  __shared__ float cgs[64 * 65];
  int t = threadIdx.x;
  int k0 = blockIdx.x * 64;
  int kmax = Gn - k0; if (kmax > 64) kmax = 64;
  for (int idx = t; idx < 2048; idx += 256) {
    int row = idx >> 6, k = idx & 63;
    w1s[k * 36 + row] = (k < kmax) ? w1[row * Gn + k0 + k] : 0.f;
  }
  for (int idx = t; idx < 4096; idx += 256) {
    int col = idx >> 6, k = idx & 63;
    cgs[k * 65 + col] = (k < kmax) ? cgW1[col * Gn + k0 + k] : 0.f;
  }
  __syncthreads();
  int col = t & 63, rg = t >> 6;
  float acc[8];
#pragma unroll
  for (int i = 0; i < 8; i++) acc[i] = 0.f;
  for (int k = 0; k < 64; k++) {
    float wk = cgs[k * 65 + col];
    const float* wr = &w1s[k * 36 + rg * 8];
    float4 r0 = *(const float4*)wr;
    float4 r1 = *(const float4*)(wr + 4);
    acc[0] = fmaf(r0.x, wk, acc[0]);
    acc[1] = fmaf(r0.y, wk, acc[1]);
    acc[2] = fmaf(r0.z, wk, acc[2]);
    acc[3] = fmaf(r0.w, wk, acc[3]);
    acc[4] = fmaf(r1.x, wk, acc[4]);
    acc[5] = fmaf(r1.y, wk, acc[5]);
    acc[6] = fmaf(r1.z, wk, acc[6]);
    acc[7] = fmaf(r1.w, wk, acc[7]);
  }
#pragma unroll
  for (int i = 0; i < 8; i++) PAR[(size_t)blockIdx.x * 2048 + (rg * 8 + i) * 64 + col] = acc[i];
}

// ---- cg2: reduce partials + 2-layer BN MLP (single block) ----
__global__ __launch_bounds__(256) void kcg2(const float* __restrict__ PAR, const float* __restrict__ cgb1,
                                            const float* __restrict__ g1, const float* __restrict__ bt1,
                                            const float* __restrict__ W2, const float* __restrict__ b2,
                                            const float* __restrict__ g2, const float* __restrict__ bt2,
                                            float* __restrict__ cg2out) {
  int t = threadIdx.x, c = t & 63, bg = t >> 6;
  __shared__ float hmid[2048], sred[4][64], qred[4][64], asc[64], bsh[64];
  float y[8];
  float ps = 0.f, pq = 0.f;
  for (int jb = 0; jb < 8; jb++) {
    int b = bg * 8 + jb;
    float v = cgb1[c];
    for (int j = 0; j < 79; j++) v += PAR[(size_t)j * 2048 + b * 64 + c];
    y[jb] = v; ps += v; pq += v * v;
  }
  sred[bg][c] = ps; qred[bg][c] = pq;
  __syncthreads();
  if (t < 64) {
    float s = sred[0][t] + sred[1][t] + sred[2][t] + sred[3][t];
    float q = qred[0][t] + qred[1][t] + qred[2][t] + qred[3][t];
    float mean = s * (1.f / 32.f), var = q * (1.f / 32.f) - mean * mean;
    float sc = g1[t] * rsqrtf(var + 1e-5f);
    asc[t] = sc; bsh[t] = bt1[t] - mean * sc;
  }
  __syncthreads();
  for (int jb = 0; jb < 8; jb++) { int b = bg * 8 + jb; hmid[b * 64 + c] = fmaxf(asc[c] * y[jb] + bsh[c], 0.f); }
  __syncthreads();
  ps = 0.f; pq = 0.f;
  for (int jb = 0; jb < 8; jb++) {
    int b = bg * 8 + jb;
    float a = b2[c];
    for (int k = 0; k < 64; k++) a += hmid[b * 64 + k] * W2[c * 64 + k];
    y[jb] = a; ps += a; pq += a * a;
  }
  sred[bg][c] = ps; qred[bg][c] = pq;
  __syncthreads();
  if (t < 64) {
    float s = sred[0][t] + sred[1][t] + sred[2][t] + sred[3][t];
    float q = qred[0][t] + qred[1][t] + qred[2][t] + qred[3][t];
    float mean = s * (1.f / 32.f), var = q * (1.f / 32.f) - mean * mean;
    float sc = g2[t] * rsqrtf(var + 1e-5f);
    asc[t] = sc; bsh[t] = bt2[t] - mean * sc;
  }
  __syncthreads();
  for (int jb = 0; jb < 8; jb++) { int b = bg * 8 + jb; cg2out[b * 64 + c] = asc[c] * y[jb] + bsh[c]; }
}

// ---- final ----
__global__ __launch_bounds__(256) void kfinal(const float* __restrict__ w1, const float* __restrict__ cg2,
                                              const float* __restrict__ iw2, const float* __restrict__ ib2,
                                              const float* __restrict__ x, float* __restrict__ out) {
  __shared__ float iws[64 * 65], cgs[2048];
  int t = threadIdx.x;
  int g0 = blockIdx.x * 64;
  for (int idx = t; idx < 64 * 65; idx += 256) {
    int gi = g0 * 65 + idx;
    iws[idx] = (gi < Gn * 65) ? iw2[gi] : 0.f;
  }
  for (int idx = t; idx < 2048; idx += 256) cgs[idx] = cg2[idx];
  __syncthreads();
  int gl = t & 63, bg = t >> 6;
  int g = g0 + gl;
  if (g >= Gn) return;
  float bias = ib2[g];
  for (int jb = 0; jb < 8; jb++) {
    int b = bg * 8 + jb;
    float acc = w1[b * Gn + g] * iws[gl * 65] + bias;
    for (int k = 0; k < 64; k++) acc += cgs[b * 64 + k] * iws[gl * 65 + 1 + k];
    out[b * Gn + g] = acc + x[b * Gn + g];
  }
}

extern "C" void kernel_launch(void* const* d_in, const int* in_sizes, int n_in,
                              void* d_out, int out_size, void* d_ws, size_t ws_size,
                              hipStream_t stream) {
  (void)in_sizes; (void)n_in; (void)out_size;
  if (ws_size < WS_FLOATS * sizeof(float)) return;

  const float* x        = (const float*)d_in[0];
  const int*   pert_idx = (const int*)d_in[1];
  const int*   ei_co    = (const int*)d_in[2];
  const float* w_co     = (const float*)d_in[3];
  const int*   ei_go    = (const int*)d_in[4];
  const float* w_go     = (const float*)d_in[5];
  const int*   ei_bg    = (const int*)d_in[6];
  const float* w_bg     = (const float*)d_in[7];
  const float* gene_tab = (const float*)d_in[8];
  const float* pos_tab  = (const float*)d_in[9];
  const float* go_tab   = (const float*)d_in[10];
  const float* bg_tab   = (const float*)d_in[11];
  const float* bn_g     = (const float*)d_in[12];
  const float* bn_b     = (const float*)d_in[13];
  const float* sg_W     = (const float*)d_in[14];
  const float* sg_b     = (const float*)d_in[15];
  const float* mlp_W    = (const float*)d_in[16];
  const float* mlp_b    = (const float*)d_in[17];
  const float* mlp_g    = (const float*)d_in[18];
  const float* mlp_bt   = (const float*)d_in[19];
  const float* rec_W1   = (const float*)d_in[20];
  const float* rec_b1   = (const float*)d_in[21];
  const float* rec_g1   = (const float*)d_in[22];
  const float* rec_bt1  = (const float*)d_in[23];
  const float* rec_W2   = (const float*)d_in[24];
  const float* rec_b2   = (const float*)d_in[25];
  const float* rec_g2   = (const float*)d_in[26];
  const float* rec_bt2  = (const float*)d_in[27];
  const float* indv_w1  = (const float*)d_in[28];
  const float* indv_b1  = (const float*)d_in[29];
  const float* cg_W1    = (const float*)d_in[30];
  const float* cg_b1    = (const float*)d_in[31];
  const float* cg_g1    = (const float*)d_in[32];
  const float* cg_bt1   = (const float*)d_in[33];
  const float* cg_W2    = (const float*)d_in[34];
  const float* cg_b2    = (const float*)d_in[35];
  const float* cg_g2    = (const float*)d_in[36];
  const float* cg_bt2   = (const float*)d_in[37];
  const float* indv_w2  = (const float*)d_in[38];
  const float* indv_b2  = (const float*)d_in[39];

  float* W = (float*)d_ws;
  float* buf0 = W + oBUF0;
  float* buf1 = W + oBUF1;
  float* PAR = W + oPAR;
  u16* Mbf   = (u16*)(W + oMBF);
  u16* W11bf = (u16*)(W + oW11BF);
  u16* W1bf  = (u16*)(W + oW1BF);
  u16* W2bf  = (u16*)(W + oW2BF);
  u16* QBF   = (u16*)(W + oRP);
  int* done  = (int*)(W + oDONE);

  int*    co_cnt    = (int*)(buf1);
  int*    bs_co     = (int*)(buf1 + 320128);
  int*    bs_go     = (int*)(buf1 + 320300);
  int*    bs_bg     = (int*)(buf1 + 320310);
  float2* co_pack   = (float2*)(buf1 + 400000);
  int*    go_cnt    = (int*)(buf1 + 3700000);
  float2* go_pack   = (float2*)(buf1 + 3720000);
  int*    bg_cnt    = (int*)(buf1 + 4000000);
  float2* bg_pack   = (float2*)(buf1 + 4020000);
  int*    co_ticket = (int*)(buf1 + 4500000);
  int*    go_ticket = (int*)(buf1 + 6200000);
  int*    bg_ticket = (int*)(buf1 + 6400000);

  // 1. zero
  kzero_all<<<681, 256, 0, stream>>>(W, W + oTB, (float*)co_cnt, (float*)go_cnt, (float*)bg_cnt);
  // 2. histograms
  khist3<<<7032, 256, 0, stream>>>(ei_co + ECO, co_cnt, co_ticket,
                                   ei_go + EGG, go_cnt, go_ticket,
                                   ei_bg + EGG, bg_cnt, bg_ticket);
  // 3-5. scans
  kscan1_3<<<167, 256, 0, stream>>>(co_cnt, go_cnt, bg_cnt, bs_co, bs_go, bs_bg);
  kscan2_3<<<3, 256, 0, stream>>>(bs_co, bs_go, bs_bg, co_cnt + Nn, go_cnt + Pn, bg_cnt + Pn);
  kscan3_3<<<167, 256, 0, stream>>>(co_cnt, go_cnt, bg_cnt, bs_co, bs_go, bs_bg);
  // 6. CSR fill
  kfillt3<<<7032, 256, 0, stream>>>(ei_co, ei_co + ECO, w_co, co_cnt, co_ticket, co_pack,
                                    ei_go, ei_go + EGG, w_go, go_cnt, go_ticket, go_pack,
                                    ei_bg, ei_bg + EGG, w_bg, bg_cnt, bg_ticket, bg_pack);
  // 7. deg-inv
  kdinvrow3<<<665, 256, 0, stream>>>(co_cnt, co_pack, W + oDEG,
                                     go_cnt, go_pack, W + oDGO,
                                     bg_cnt, bg_pack, W + oDBG);
  // 8. renorms
  krenorm4<<<640, 256, 0, stream>>>(gene_tab, W + oRG, W + oSG, pos_tab, W + oRP,
                                    go_tab, W + oRGO, bg_tab, W + oRBG);
  // 9. gathers
  kgather3<<<3072, 256, 0, stream>>>(co_cnt, co_pack, W + oDEG, W + oRP, (u16*)buf0,
                                     go_cnt, go_pack, W + oDGO, W + oRGO, W + oAGO,
                                     bg_cnt, bg_pack, W + oDBG, W + oRBG, W + oABG);
  // 10. prep (smallmats + SG finalize + weight cvts)
  kprep<<<84, 256, 0, stream>>>(mlp_W, mlp_b, sg_W, sg_b, W + oSG, bn_g, bn_b,
                                W + oM, W + oCvec, W + oM1, W + oM2, W + oCcP,
                                W + oAG, W + oBG, rec_W1, rec_W2, W11bf, W1bf, W2bf);
  // 11. Q gemm (bf16) + M cvt  (QBF overwrites oRP after co-gather)
  kqgemm<<<95, 256, 0, stream>>>(W + oRG, W + oAG, W + oBG, mlp_W + 8192, W + oCvec, QBF, W + oM, Mbf);
  // 12-13. pert path
  gemm64k<true, false, true><<<79, 256, 0, stream>>>(
      W + oAGO, W + oABG, W + oM1, W + oM2, W + oCcP, nullptr, nullptr,
      W + oM1B, W + oSP1, Pn, done + 0, mlp_g, mlp_bt, W + oAP1, W + oBP1, 1.f / Pn);
  gemm64k<false, true, false><<<79, 256, 0, stream>>>(
      W + oM1B, nullptr, mlp_W + 4096, nullptr, mlp_b + 64, W + oAP1, W + oBP1,
      W + oM2B, W + oSP2, Pn, nullptr, nullptr, nullptr, nullptr, nullptr, 0.f);
  // 14. t1
  gemm_mf64<2, 4, false, false, true, false, true><<<NT64, 256, 0, stream>>>(
      (const u16*)buf0, Mbf, W + oZERO, nullptr, nullptr, QBF, (u16*)buf1, 64,
      W + oS1, nullptr, done + 1, mlp_g + 128, mlp_bt + 128, W + oA1, W + oB1, 1.f / Nn);
  // 15. t2 (+Tb)
  gemm_mf64<2, 4, true, false, false, true, true><<<NT64, 256, 0, stream>>>(
      (const u16*)buf1, W11bf, mlp_b + 192, W + oA1, W + oB1, nullptr, (u16*)buf0, 64,
      W + oS2, W + oTB, done + 2, mlp_g + 192, mlp_bt + 192, W + oA2, W + oB2, 1.f / Nn);
  // 16. SP2 finalize + pert-MLP + analytic S3
  kembS3<<<1, 256, 0, stream>>>(W + oSP2, mlp_g + 64, mlp_bt + 64, W + oM2B, pert_idx,
                                mlp_W + 16384, mlp_b + 256, mlp_g + 256, mlp_bt + 256,
                                W + oS2, W + oA2, W + oB2, W + oTB, bn_g + 64, bn_b + 64,
                                W + oAvec, W + oE2);
  // 17. r1 (both halves)
  gemm_mf64<2, 8, true, true, false, false, true><<<NT64, 256, 0, stream>>>(
      (const u16*)buf0, W1bf, rec_b1, W + oAvec, W + oE2, nullptr, (u16*)buf1, 128,
      W + oS4, nullptr, done + 3, rec_g1, rec_bt1, W + oA4, W + oB4, 1.f / Nn);
  // 18. r2
  gemm_mf64<4, 4, true, false, false, false, true><<<NT64, 256, 0, stream>>>(
      (const u16*)buf1, W2bf, rec_b2, W + oA4, W + oB4, nullptr, (u16*)buf0, 64,
      W + oS5, nullptr, done + 4, rec_g2, rec_bt2, W + oA5, W + oB5, 1.f / Nn);
  // 19. w1
  k13_kernel<<<(Nn * 16 + 255) / 256, 256, 0, stream>>>((const u16*)buf0, W + oA5, W + oB5,
                                                        indv_w1, indv_b1, W + oW1, Nn);
  // 20-21. cross-gene
  kcg1s<<<79, 256, 0, stream>>>(W + oW1, cg_W1, PAR);
  kcg2<<<1, 256, 0, stream>>>(PAR, cg_b1, cg_g1, cg_bt1, cg_W2, cg_b2, cg_g2, cg_bt2, W + oCG2);
  // 22. final
  kfinal<<<79, 256, 0, stream>>>(W + oW1, W + oCG2, indv_w2, indv_b2, x, (float*)d_out);
}

// Round 10
// 1126.296 us; speedup vs baseline: 1.4947x; 1.4947x over previous
//
#include <hip/hip_runtime.h>

typedef unsigned int u32;
typedef unsigned short u16;

// Problem constants (fixed by the reference)
constexpr int Gn  = 5000;     // genes
constexpr int Bn  = 32;       // batch graphs
constexpr int Pn  = 5000;     // perts
constexpr int Nn  = Bn * Gn;  // 160000
constexpr int ECO = 1600000;
constexpr int EGG = 100000;
constexpr int NTILES = Nn / 128;  // 1250, exact

// ---- workspace layout (float offsets) ----
constexpr int oS1 = 0, oS2 = 128, oS4 = 384, oS5 = 640, oSG = 768, oSP1 = 896, oSP2 = 1024;
constexpr int oZERO = 1536;  // stays zero (bias for t1)
constexpr int oA1 = 2048, oB1 = 2112, oA2 = 2176, oB2 = 2240;
constexpr int oA4 = 2304, oB4 = 2432;            // 128 each
constexpr int oA5 = 2560, oB5 = 2624;
constexpr int oAG = 2688, oBG = 2752;
constexpr int oAP1 = 2816, oBP1 = 2880, oAP2 = 2944, oBP2 = 3008;
constexpr int oAvec = 3072, oCvec = 3136, oCcP = 3200;
constexpr int oM  = 4096, oM1 = 8192, oM2 = 12288;
constexpr int oE2 = 16384, oEMB = 18432, oCGRAW = 20480, oCG2 = 22528;
// oCGRAW doubles as Tb (per-batch col sums of t2) — consumed by kfinS3an BEFORE kinitcg rewrites it
constexpr int oRG  = 24576;
constexpr int oRP  = oRG  + Gn * 64;
constexpr int oQ   = oRP  + Gn * 64;
constexpr int oRGO = oQ   + Gn * 64;
constexpr int oRBG = oRGO + Pn * 64;
constexpr int oAGO = oRBG + Pn * 64;
constexpr int oABG = oAGO + Pn * 64;
constexpr int oM1B = oABG + Pn * 64;
constexpr int oM2B = oM1B + Pn * 64;
constexpr int oDGO = oM2B + Pn * 64;
constexpr int oDBG = oDGO + Pn;
constexpr int oDEG = oDBG + Pn;
constexpr int oW1  = oDEG + Nn;
constexpr int oBUF0 = oW1 + Nn;
constexpr int oBUF1 = oBUF0 + Nn * 64;
constexpr size_t WS_FLOATS = (size_t)oBUF1 + (size_t)Nn * 64;  // ~95 MB

__device__ inline u16 f2bf(float f) {
  u32 u = __float_as_uint(f);
  u = (u + 0x7fffu + ((u >> 16) & 1u)) >> 16;
  return (u16)u;
}
__device__ inline float bflo(u32 v) { return __uint_as_float(v << 16); }
__device__ inline float bfhi(u32 v) { return __uint_as_float(v & 0xffff0000u); }

#define XC(v, kk) ((kk) == 0 ? (v).x : (kk) == 1 ? (v).y : (kk) == 2 ? (v).z : (v).w)

__global__ __launch_bounds__(256) void kzero(float* p, int n) {
  int i = blockIdx.x * 256 + threadIdx.x;
  if (i < n) p[i] = 0.f;
}

// row-wise L2 renorm (norm clipped to <=1); optional column stats of the output
__global__ __launch_bounds__(256) void krenorm(const float* __restrict__ in, float* __restrict__ out,
                                               float* __restrict__ stats, int rows) {
  int lane = threadIdx.x & 63, wv = threadIdx.x >> 6;
  int gw = blockIdx.x * 4 + wv, nw = gridDim.x * 4;
  float ps = 0.f, pq = 0.f;
  for (int r = gw; r < rows; r += nw) {
    float v = in[r * 64 + lane];
    float sq = v * v;
    for (int off = 32; off; off >>= 1) sq += __shfl_xor(sq, off, 64);
    float nn = sqrtf(sq);
    float s = fminf(1.f, 1.f / fmaxf(nn, 1e-12f));
    float o = v * s;
    out[r * 64 + lane] = o;
    ps += o; pq += o * o;
  }
  if (!stats) return;
  __shared__ float red[4][64], red2[4][64];
  red[wv][lane] = ps; red2[wv][lane] = pq;
  __syncthreads();
  if (wv == 0) {
    float s = red[0][lane] + red[1][lane] + red[2][lane] + red[3][lane];
    float q = red2[0][lane] + red2[1][lane] + red2[2][lane] + red2[3][lane];
    atomicAdd(&stats[lane], s);
    atomicAdd(&stats[64 + lane], q);
  }
}

// finalize BN: a = g*rsqrt(var+eps), b = bt - mean*a
__global__ void kfin(const float* __restrict__ stats, const float* __restrict__ g,
                     const float* __restrict__ bt, float* __restrict__ a, float* __restrict__ b,
                     int cols, float invn) {
  int c = blockIdx.x * 64 + threadIdx.x;
  if (c >= cols) return;
  float mean = stats[c] * invn;
  float var = stats[cols + c] * invn - mean * mean;
  float sc = g[c] * rsqrtf(var + 1e-5f);
  a[c] = sc;
  b[c] = bt[c] - mean * sc;
}

// Mout = alpha * A @ Bm  (64x64 each); optional cvec = bias + beta * A @ (bv1+bv2)
__global__ __launch_bounds__(256) void ksmallmat(const float* __restrict__ A, const float* __restrict__ Bm,
                                                 float alpha, const float* __restrict__ bias,
                                                 const float* __restrict__ bv1, const float* __restrict__ bv2,
                                                 float beta, float* __restrict__ Mout, float* __restrict__ cvec) {
  __shared__ float As[4096], Bs[4096];
  int t = threadIdx.x;
  for (int m = 0; m < 16; m++) { As[m * 256 + t] = A[m * 256 + t]; Bs[m * 256 + t] = Bm[m * 256 + t]; }
  __syncthreads();
  int j = t & 63, ig = t >> 6;
  for (int ii = 0; ii < 16; ii++) {
    int i = ig * 16 + ii;
    float acc = 0.f;
    for (int k = 0; k < 64; k++) acc += As[i * 64 + k] * Bs[k * 64 + j];
    Mout[i * 64 + j] = alpha * acc;
  }
  if (cvec && t < 64) {
    float acc = bias ? bias[t] : 0.f;
    for (int k = 0; k < 64; k++) {
      float bb = (bv1 ? bv1[k] : 0.f) + (bv2 ? bv2[k] : 0.f);
      acc += beta * As[t * 64 + k] * bb;
    }
    cvec[t] = acc;
  }
}

// histogram with ticket: one atomic per edge
__global__ __launch_bounds__(256) void khist(const int* __restrict__ dst, int* __restrict__ cnt,
                                             int* __restrict__ ticket, int E) {
  int e = blockIdx.x * 256 + threadIdx.x;
  if (e < E) ticket[e] = atomicAdd(&cnt[dst[e]], 1);
}

// ---- block scan (1024 elems/block) ----
__global__ __launch_bounds__(256) void kscan1(const int* __restrict__ cnt, int* __restrict__ bsum, int n) {
  __shared__ int sh[256];
  int b = blockIdx.x, t = threadIdx.x;
  int base = b * 1024 + t * 4;
  int s = 0;
#pragma unroll
  for (int j = 0; j < 4; j++) { int i = base + j; if (i < n) s += cnt[i]; }
  sh[t] = s; __syncthreads();
  for (int d = 128; d; d >>= 1) { if (t < d) sh[t] += sh[t + d]; __syncthreads(); }
  if (t == 0) bsum[b] = sh[0];
}
__global__ __launch_bounds__(256) void kscan2(int* bsum, int nb, int* off_n) {
  __shared__ int sh[256];
  int t = threadIdx.x;
  int v = (t < nb) ? bsum[t] : 0;
  sh[t] = v;
  __syncthreads();
  for (int d = 1; d < 256; d <<= 1) {
    int u = (t >= d) ? sh[t - d] : 0;
    __syncthreads();
    sh[t] += u;
    __syncthreads();
  }
  if (t < nb) bsum[t] = sh[t] - v;  // exclusive
  if (t == nb - 1 && off_n) *off_n = sh[t];
}
__global__ __launch_bounds__(256) void kscan3(int* __restrict__ cnt, const int* __restrict__ bsum, int n) {
  __shared__ int sh[256];
  int b = blockIdx.x, t = threadIdx.x;
  int base = b * 1024 + t * 4;
  int c0 = (base + 0 < n) ? cnt[base + 0] : 0;
  int c1 = (base + 1 < n) ? cnt[base + 1] : 0;
  int c2 = (base + 2 < n) ? cnt[base + 2] : 0;
  int c3 = (base + 3 < n) ? cnt[base + 3] : 0;
  int tot = c0 + c1 + c2 + c3;
  sh[t] = tot; __syncthreads();
  for (int d = 1; d < 256; d <<= 1) {
    int v = (t >= d) ? sh[t - d] : 0;
    __syncthreads();
    sh[t] += v;
    __syncthreads();
  }
  int excl = sh[t] - tot + bsum[b];
  if (base + 0 < n) cnt[base + 0] = excl;
  if (base + 1 < n) cnt[base + 1] = excl + c0;
  if (base + 2 < n) cnt[base + 2] = excl + c0 + c1;
  if (base + 3 < n) cnt[base + 3] = excl + c0 + c1 + c2;
}

// atomic-free CSR fill using tickets: pack[off[d]+ticket] = (w, src_full)
__global__ __launch_bounds__(256) void kfillt(const int* __restrict__ src, const int* __restrict__ dst,
                                              const float* __restrict__ w, const int* __restrict__ off,
                                              const int* __restrict__ ticket, float2* __restrict__ pack, int E) {
  int e = blockIdx.x * 256 + threadIdx.x;
  if (e >= E) return;
  int d = dst[e];
  int pos = off[d] + ticket[e];
  pack[pos] = make_float2(w[e], __int_as_float(src[e]));
}

// per-row: deg = 1 + sum(w) over CSR row; dinv = rsqrt(deg)
__global__ __launch_bounds__(256) void kdinvrow(const int* __restrict__ off, const float2* __restrict__ pack,
                                                float* __restrict__ dinv, int n) {
  int i = blockIdx.x * 256 + threadIdx.x;
  if (i >= n) return;
  int b0 = off[i], b1 = off[i + 1];
  float s = 1.f;
  for (int j = b0; j < b1; j++) s += pack[j].x;
  dinv[i] = rsqrtf(s);
}

// wave-per-row CSR gather with cooperative pack load + shuffle broadcast
template <bool OBF>
__global__ __launch_bounds__(256) void kgather(const int* __restrict__ off, const float2* __restrict__ pack,
                                               const float* __restrict__ dinv, const float* __restrict__ tab,
                                               float* __restrict__ aggf, u16* __restrict__ aggb, int n) {
  int lane = threadIdx.x & 63;
  int wv = blockIdx.x * 4 + (threadIdx.x >> 6);
  int nw = gridDim.x * 4;
  for (int i = wv; i < n; i += nw) {
    int b0 = off[i], b1 = off[i + 1];
    float di = dinv[i];
    float acc = di * tab[(i % Gn) * 64 + lane];
    for (int base = b0; base < b1; base += 64) {
      int m = b1 - base; if (m > 64) m = 64;
      float cj = 0.f; int idxj = 0;
      if (lane < m) {
        float2 p = pack[base + lane];
        int s = __float_as_int(p.y);
        cj = p.x * dinv[s];
        idxj = (s % Gn) * 64;
      }
      int j = 0;
      for (; j + 1 < m; j += 2) {
        float c0 = __shfl(cj, j, 64);     int i0 = __shfl(idxj, j, 64);
        float c1 = __shfl(cj, j + 1, 64); int i1 = __shfl(idxj, j + 1, 64);
        float t0 = tab[i0 + lane];
        float t1 = tab[i1 + lane];
        acc = fmaf(c0, t0, acc);
        acc = fmaf(c1, t1, acc);
      }
      if (j < m) {
        float c0 = __shfl(cj, j, 64); int i0 = __shfl(idxj, j, 64);
        acc = fmaf(c0, tab[i0 + lane], acc);
      }
    }
    acc *= di;
    if (OBF) aggb[(size_t)i * 64 + lane] = f2bf(acc);
    else aggf[(size_t)i * 64 + lane] = acc;
  }
}

// ===================== big-N tiled GEMM (128 rows x 64 cols, K=64), bf16 in/out =====================
// Optional TB: per-batch column sums of output (pre-rounding) into Tb[32][64], per-tile LDS-reduced.
template <bool PRE, bool EB, bool PERG, bool TB>
__global__ __launch_bounds__(256, 3) void gemm_big(
    const u16* __restrict__ Xb, const float* __restrict__ Wg,
    const float* __restrict__ bias, const float* __restrict__ pa, const float* __restrict__ pb,
    const float* __restrict__ perg, u16* __restrict__ Ybf, int obpitch,
    float* __restrict__ stats, int sqoff, float* __restrict__ Tb) {
  __shared__ float xs[128 * 68];
  __shared__ float wt[64 * 68];
  __shared__ float sstat[128];
  __shared__ float tbs[128];
  int t = threadIdx.x, cg = t & 7, rg = t >> 3;
  for (int idx = t; idx < 4096; idx += 256) {
    int oc = idx >> 6, k = idx & 63;
    wt[k * 68 + oc] = Wg[idx];
  }
  float sS[8], sQ[8];
#pragma unroll
  for (int j = 0; j < 8; j++) { sS[j] = 0.f; sQ[j] = 0.f; }
  float bb[8];
  {
    float4 b0 = *(const float4*)&bias[cg * 8];
    float4 b1 = *(const float4*)&bias[cg * 8 + 4];
    bb[0] = b0.x; bb[1] = b0.y; bb[2] = b0.z; bb[3] = b0.w;
    bb[4] = b1.x; bb[5] = b1.y; bb[6] = b1.z; bb[7] = b1.w;
  }
  for (int tile = blockIdx.x; tile < NTILES; tile += gridDim.x) {
    int R0 = tile * 128;
    int b0t = R0 / Gn, bEt = (R0 + 127) / Gn;
    float tS[2][8];
    if (TB) {
#pragma unroll
      for (int s = 0; s < 2; s++)
#pragma unroll
        for (int j = 0; j < 8; j++) tS[s][j] = 0.f;
    }
    __syncthreads();
#pragma unroll
    for (int m = 0; m < 4; m++) {
      int f = m * 256 + t;
      int r = f >> 3, c8 = (f & 7) * 8;
      uint4 u = *(const uint4*)&Xb[(size_t)(R0 + r) * 64 + c8];
      float v[8] = {bflo(u.x), bfhi(u.x), bflo(u.y), bfhi(u.y),
                    bflo(u.z), bfhi(u.z), bflo(u.w), bfhi(u.w)};
      if (PRE) {
        float4 A0 = *(const float4*)&pa[c8];
        float4 A1 = *(const float4*)&pa[c8 + 4];
        const float* pbb = EB ? &pb[((R0 + r) / Gn) * 64] : pb;
        float4 B0 = *(const float4*)&pbb[c8];
        float4 B1 = *(const float4*)&pbb[c8 + 4];
        v[0] = fmaxf(fmaf(A0.x, v[0], B0.x), 0.f);
        v[1] = fmaxf(fmaf(A0.y, v[1], B0.y), 0.f);
        v[2] = fmaxf(fmaf(A0.z, v[2], B0.z), 0.f);
        v[3] = fmaxf(fmaf(A0.w, v[3], B0.w), 0.f);
        v[4] = fmaxf(fmaf(A1.x, v[4], B1.x), 0.f);
        v[5] = fmaxf(fmaf(A1.y, v[5], B1.y), 0.f);
        v[6] = fmaxf(fmaf(A1.z, v[6], B1.z), 0.f);
        v[7] = fmaxf(fmaf(A1.w, v[7], B1.w), 0.f);
      }
      *(float4*)&xs[r * 68 + c8] = make_float4(v[0], v[1], v[2], v[3]);
      *(float4*)&xs[r * 68 + c8 + 4] = make_float4(v[4], v[5], v[6], v[7]);
    }
    __syncthreads();
    float acc[4][8];
#pragma unroll
    for (int i = 0; i < 4; i++)
#pragma unroll
      for (int j = 0; j < 8; j++) acc[i][j] = 0.f;
#pragma unroll
    for (int kc = 0; kc < 16; kc++) {
      float4 x0 = *(const float4*)&xs[(rg * 4 + 0) * 68 + kc * 4];
      float4 x1 = *(const float4*)&xs[(rg * 4 + 1) * 68 + kc * 4];
      float4 x2 = *(const float4*)&xs[(rg * 4 + 2) * 68 + kc * 4];
      float4 x3 = *(const float4*)&xs[(rg * 4 + 3) * 68 + kc * 4];
#pragma unroll
      for (int kk = 0; kk < 4; kk++) {
        const float* wr = &wt[(kc * 4 + kk) * 68 + cg * 8];
        float4 w0 = *(const float4*)wr;
        float4 w1 = *(const float4*)(wr + 4);
        float wv[8] = {w0.x, w0.y, w0.z, w0.w, w1.x, w1.y, w1.z, w1.w};
        float a0 = XC(x0, kk), a1 = XC(x1, kk), a2 = XC(x2, kk), a3 = XC(x3, kk);
#pragma unroll
        for (int j = 0; j < 8; j++) {
          acc[0][j] = fmaf(a0, wv[j], acc[0][j]);
          acc[1][j] = fmaf(a1, wv[j], acc[1][j]);
          acc[2][j] = fmaf(a2, wv[j], acc[2][j]);
          acc[3][j] = fmaf(a3, wv[j], acc[3][j]);
        }
      }
    }
#pragma unroll
    for (int i = 0; i < 4; i++) {
      int grow = R0 + rg * 4 + i;
      float v[8];
#pragma unroll
      for (int j = 0; j < 8; j++) v[j] = acc[i][j] + bb[j];
      if (PERG) {
        int qr = grow % Gn;
        float4 q0 = *(const float4*)&perg[(size_t)qr * 64 + cg * 8];
        float4 q1 = *(const float4*)&perg[(size_t)qr * 64 + cg * 8 + 4];
        v[0] += q0.x; v[1] += q0.y; v[2] += q0.z; v[3] += q0.w;
        v[4] += q1.x; v[5] += q1.y; v[6] += q1.z; v[7] += q1.w;
      }
#pragma unroll
      for (int j = 0; j < 8; j++) { sS[j] += v[j]; sQ[j] += v[j] * v[j]; }
      if (TB) {
        int slot = (grow / Gn) != b0t;
#pragma unroll
        for (int j = 0; j < 8; j++) tS[slot][j] += v[j];
      }
      uint4 o;
      o.x = (u32)f2bf(v[0]) | ((u32)f2bf(v[1]) << 16);
      o.y = (u32)f2bf(v[2]) | ((u32)f2bf(v[3]) << 16);
      o.z = (u32)f2bf(v[4]) | ((u32)f2bf(v[5]) << 16);
      o.w = (u32)f2bf(v[6]) | ((u32)f2bf(v[7]) << 16);
      *(uint4*)&Ybf[(size_t)grow * obpitch + cg * 8] = o;
    }
    if (TB) {
      __syncthreads();
      for (int idx = t; idx < 128; idx += 256) tbs[idx] = 0.f;
      __syncthreads();
#pragma unroll
      for (int j = 0; j < 8; j++) {
        atomicAdd(&tbs[cg * 8 + j], tS[0][j]);
        atomicAdd(&tbs[64 + cg * 8 + j], tS[1][j]);
      }
      __syncthreads();
      if (t < 64) atomicAdd(&Tb[b0t * 64 + t], tbs[t]);
      else if (t < 128 && bEt != b0t) atomicAdd(&Tb[bEt * 64 + (t - 64)], tbs[t - 64]);
    }
  }
  __syncthreads();
  for (int idx = t; idx < 128; idx += 256) sstat[idx] = 0.f;
  __syncthreads();
#pragma unroll
  for (int j = 0; j < 8; j++) {
    atomicAdd(&sstat[cg * 8 + j], sS[j]);
    atomicAdd(&sstat[64 + cg * 8 + j], sQ[j]);
  }
  __syncthreads();
  for (int idx = t; idx < 64; idx += 256) {
    atomicAdd(&stats[idx], sstat[idx]);
    atomicAdd(&stats[sqoff + idx], sstat[64 + idx]);
  }
}

// r1 merged: base2 = relu(Avec*t2 + e2[b]) staged once; both 64-col halves of r1 per tile.
__global__ __launch_bounds__(256, 3) void gemm_r1(
    const u16* __restrict__ Xb, const float* __restrict__ W1, const float* __restrict__ b1,
    const float* __restrict__ pa, const float* __restrict__ pb,
    u16* __restrict__ Ybf, float* __restrict__ stats) {
  __shared__ float xs[128 * 68];
  __shared__ float wt[64 * 68];
  __shared__ float sstat[256];
  int t = threadIdx.x, cg = t & 7, rg = t >> 3;
  float sS[2][8], sQ[2][8];
#pragma unroll
  for (int h = 0; h < 2; h++)
#pragma unroll
    for (int j = 0; j < 8; j++) { sS[h][j] = 0.f; sQ[h][j] = 0.f; }
  float bb[2][8];
#pragma unroll
  for (int h = 0; h < 2; h++) {
    float4 b0 = *(const float4*)&b1[h * 64 + cg * 8];
    float4 b1v = *(const float4*)&b1[h * 64 + cg * 8 + 4];
    bb[h][0] = b0.x; bb[h][1] = b0.y; bb[h][2] = b0.z; bb[h][3] = b0.w;
    bb[h][4] = b1v.x; bb[h][5] = b1v.y; bb[h][6] = b1v.z; bb[h][7] = b1v.w;
  }
  for (int tile = blockIdx.x; tile < NTILES; tile += gridDim.x) {
    int R0 = tile * 128;
    __syncthreads();
#pragma unroll
    for (int m = 0; m < 4; m++) {
      int f = m * 256 + t;
      int r = f >> 3, c8 = (f & 7) * 8;
      uint4 u = *(const uint4*)&Xb[(size_t)(R0 + r) * 64 + c8];
      float v[8] = {bflo(u.x), bfhi(u.x), bflo(u.y), bfhi(u.y),
                    bflo(u.z), bfhi(u.z), bflo(u.w), bfhi(u.w)};
      float4 A0 = *(const float4*)&pa[c8];
      float4 A1 = *(const float4*)&pa[c8 + 4];
      const float* pbb = &pb[((R0 + r) / Gn) * 64];
      float4 B0 = *(const float4*)&pbb[c8];
      float4 B1 = *(const float4*)&pbb[c8 + 4];
      v[0] = fmaxf(fmaf(A0.x, v[0], B0.x), 0.f);
      v[1] = fmaxf(fmaf(A0.y, v[1], B0.y), 0.f);
      v[2] = fmaxf(fmaf(A0.z, v[2], B0.z), 0.f);
      v[3] = fmaxf(fmaf(A0.w, v[3], B0.w), 0.f);
      v[4] = fmaxf(fmaf(A1.x, v[4], B1.x), 0.f);
      v[5] = fmaxf(fmaf(A1.y, v[5], B1.y), 0.f);
      v[6] = fmaxf(fmaf(A1.z, v[6], B1.z), 0.f);
      v[7] = fmaxf(fmaf(A1.w, v[7], B1.w), 0.f);
      *(float4*)&xs[r * 68 + c8] = make_float4(v[0], v[1], v[2], v[3]);
      *(float4*)&xs[r * 68 + c8 + 4] = make_float4(v[4], v[5], v[6], v[7]);
    }
    for (int hh = 0; hh < 2; hh++) {
      for (int idx = t; idx < 4096; idx += 256) {
        int oc = idx >> 6, k = idx & 63;
        wt[k * 68 + oc] = W1[(hh * 64 + oc) * 64 + k];
      }
      __syncthreads();
      float acc[4][8];
#pragma unroll
      for (int i = 0; i < 4; i++)
#pragma unroll
        for (int j = 0; j < 8; j++) acc[i][j] = 0.f;
#pragma unroll
      for (int kc = 0; kc < 16; kc++) {
        float4 x0 = *(const float4*)&xs[(rg * 4 + 0) * 68 + kc * 4];
        float4 x1 = *(const float4*)&xs[(rg * 4 + 1) * 68 + kc * 4];
        float4 x2 = *(const float4*)&xs[(rg * 4 + 2) * 68 + kc * 4];
        float4 x3 = *(const float4*)&xs[(rg * 4 + 3) * 68 + kc * 4];
#pragma unroll
        for (int kk = 0; kk < 4; kk++) {
          const float* wr = &wt[(kc * 4 + kk) * 68 + cg * 8];
          float4 w0 = *(const float4*)wr;
          float4 w1 = *(const float4*)(wr + 4);
          float wv[8] = {w0.x, w0.y, w0.z, w0.w, w1.x, w1.y, w1.z, w1.w};
          float a0 = XC(x0, kk), a1 = XC(x1, kk), a2 = XC(x2, kk), a3 = XC(x3, kk);
#pragma unroll
          for (int j = 0; j < 8; j++) {
            acc[0][j] = fmaf(a0, wv[j], acc[0][j]);
            acc[1][j] = fmaf(a1, wv[j], acc[1][j]);
            acc[2][j] = fmaf(a2, wv[j], acc[2][j]);
            acc[3][j] = fmaf(a3, wv[j], acc[3][j]);
          }
        }
      }
#pragma unroll
      for (int i = 0; i < 4; i++) {
        int grow = R0 + rg * 4 + i;
        float v[8];
#pragma unroll
        for (int j = 0; j < 8; j++) {
          v[j] = acc[i][j] + bb[hh][j];
          sS[hh][j] += v[j]; sQ[hh][j] += v[j] * v[j];
        }
        uint4 o;
        o.x = (u32)f2bf(v[0]) | ((u32)f2bf(v[1]) << 16);
        o.y = (u32)f2bf(v[2]) | ((u32)f2bf(v[3]) << 16);
        o.z = (u32)f2bf(v[4]) | ((u32)f2bf(v[5]) << 16);
        o.w = (u32)f2bf(v[6]) | ((u32)f2bf(v[7]) << 16);
        *(uint4*)&Ybf[(size_t)grow * 128 + hh * 64 + cg * 8] = o;
      }
      __syncthreads();
    }
  }
  for (int idx = t; idx < 256; idx += 256) sstat[idx] = 0.f;
  __syncthreads();
#pragma unroll
  for (int h = 0; h < 2; h++)
#pragma unroll
    for (int j = 0; j < 8; j++) {
      atomicAdd(&sstat[h * 64 + cg * 8 + j], sS[h][j]);
      atomicAdd(&sstat[128 + h * 64 + cg * 8 + j], sQ[h][j]);
    }
  __syncthreads();
  for (int idx = t; idx < 256; idx += 256) atomicAdd(&stats[idx], sstat[idx]);
}

// k11: r2 = relu(a4*r1+b4) @ W2^T + b2 ; K=128 (two staged halves), r1 bf16 pitch 128, out bf16 pitch 64
__global__ __launch_bounds__(256, 3) void gemm_k11(
    const u16* __restrict__ Xbf, const float* __restrict__ W2,
    const float* __restrict__ bias, const float* __restrict__ a4, const float* __restrict__ b4,
    u16* __restrict__ Ybf, float* __restrict__ stats) {
  __shared__ float xs[128 * 68];
  __shared__ float wt[64 * 68];
  __shared__ float sstat[128];
  int t = threadIdx.x, cg = t & 7, rg = t >> 3;
  float sS[8], sQ[8];
#pragma unroll
  for (int j = 0; j < 8; j++) { sS[j] = 0.f; sQ[j] = 0.f; }
  float bb[8];
  {
    float4 b0 = *(const float4*)&bias[cg * 8];
    float4 b1 = *(const float4*)&bias[cg * 8 + 4];
    bb[0] = b0.x; bb[1] = b0.y; bb[2] = b0.z; bb[3] = b0.w;
    bb[4] = b1.x; bb[5] = b1.y; bb[6] = b1.z; bb[7] = b1.w;
  }
  for (int tile = blockIdx.x; tile < NTILES; tile += gridDim.x) {
    int R0 = tile * 128;
    float acc[4][8];
#pragma unroll
    for (int i = 0; i < 4; i++)
#pragma unroll
      for (int j = 0; j < 8; j++) acc[i][j] = 0.f;
    for (int hh = 0; hh < 2; hh++) {
      __syncthreads();
      for (int idx = t; idx < 4096; idx += 256) {
        int oc = idx >> 6, kl = idx & 63;
        wt[kl * 68 + oc] = W2[oc * 128 + hh * 64 + kl];
      }
#pragma unroll
      for (int m = 0; m < 4; m++) {
        int f = m * 256 + t;
        int r = f >> 3, ch = f & 7;
        const uint4* p = (const uint4*)&Xbf[(size_t)(R0 + r) * 128 + hh * 64 + ch * 8];
        uint4 u = *p;
        int kb = hh * 64 + ch * 8;
        float4 A0 = *(const float4*)&a4[kb];
        float4 A1 = *(const float4*)&a4[kb + 4];
        float4 B0 = *(const float4*)&b4[kb];
        float4 B1 = *(const float4*)&b4[kb + 4];
        float4 v0, v1;
        v0.x = fmaxf(fmaf(A0.x, bflo(u.x), B0.x), 0.f);
        v0.y = fmaxf(fmaf(A0.y, bfhi(u.x), B0.y), 0.f);
        v0.z = fmaxf(fmaf(A0.z, bflo(u.y), B0.z), 0.f);
        v0.w = fmaxf(fmaf(A0.w, bfhi(u.y), B0.w), 0.f);
        v1.x = fmaxf(fmaf(A1.x, bflo(u.z), B1.x), 0.f);
        v1.y = fmaxf(fmaf(A1.y, bfhi(u.z), B1.y), 0.f);
        v1.z = fmaxf(fmaf(A1.z, bflo(u.w), B1.z), 0.f);
        v1.w = fmaxf(fmaf(A1.w, bfhi(u.w), B1.w), 0.f);
        *(float4*)&xs[r * 68 + ch * 8] = v0;
        *(float4*)&xs[r * 68 + ch * 8 + 4] = v1;
      }
      __syncthreads();
#pragma unroll
      for (int kc = 0; kc < 16; kc++) {
        float4 x0 = *(const float4*)&xs[(rg * 4 + 0) * 68 + kc * 4];
        float4 x1 = *(const float4*)&xs[(rg * 4 + 1) * 68 + kc * 4];
        float4 x2 = *(const float4*)&xs[(rg * 4 + 2) * 68 + kc * 4];
        float4 x3 = *(const float4*)&xs[(rg * 4 + 3) * 68 + kc * 4];
#pragma unroll
        for (int kk = 0; kk < 4; kk++) {
          const float* wr = &wt[(kc * 4 + kk) * 68 + cg * 8];
          float4 w0 = *(const float4*)wr;
          float4 w1 = *(const float4*)(wr + 4);
          float wv[8] = {w0.x, w0.y, w0.z, w0.w, w1.x, w1.y, w1.z, w1.w};
          float a0 = XC(x0, kk), a1 = XC(x1, kk), a2 = XC(x2, kk), a3 = XC(x3, kk);
#pragma unroll
          for (int j = 0; j < 8; j++) {
            acc[0][j] = fmaf(a0, wv[j], acc[0][j]);
            acc[1][j] = fmaf(a1, wv[j], acc[1][j]);
            acc[2][j] = fmaf(a2, wv[j], acc[2][j]);
            acc[3][j] = fmaf(a3, wv[j], acc[3][j]);
          }
        }
      }
    }
#pragma unroll
    for (int i = 0; i < 4; i++) {
      int grow = R0 + rg * 4 + i;
      float v[8];
#pragma unroll
      for (int j = 0; j < 8; j++) {
        v[j] = acc[i][j] + bb[j];
        sS[j] += v[j]; sQ[j] += v[j] * v[j];
      }
      uint4 o;
      o.x = (u32)f2bf(v[0]) | ((u32)f2bf(v[1]) << 16);
      o.y = (u32)f2bf(v[2]) | ((u32)f2bf(v[3]) << 16);
      o.z = (u32)f2bf(v[4]) | ((u32)f2bf(v[5]) << 16);
      o.w = (u32)f2bf(v[6]) | ((u32)f2bf(v[7]) << 16);
      *(uint4*)&Ybf[(size_t)grow * 64 + cg * 8] = o;
    }
  }
  __syncthreads();
  for (int idx = t; idx < 128; idx += 256) sstat[idx] = 0.f;
  __syncthreads();
#pragma unroll
  for (int j = 0; j < 8; j++) {
    atomicAdd(&sstat[cg * 8 + j], sS[j]);
    atomicAdd(&sstat[64 + cg * 8 + j], sQ[j]);
  }
  __syncthreads();
  for (int idx = t; idx < 128; idx += 256) atomicAdd(&stats[idx], sstat[idx]);
}

// ===================== small GEMM (Pn/Gn paths, fp32) =====================
template <bool TWO, bool PRE, bool PRELU, bool PERG, bool STATS>
__global__ __launch_bounds__(256) void gemm64k(
    const float* __restrict__ X, const float* __restrict__ Xb,
    const float* __restrict__ Wm, const float* __restrict__ Wb,
    const float* __restrict__ bias,
    const float* __restrict__ pa, const float* __restrict__ pb,
    const float* __restrict__ perg, int tabrows,
    float* __restrict__ Y, float* __restrict__ stats, int rows) {
  __shared__ float xs[4096];
  __shared__ float red[4][64], red2[4][64];
  int t = threadIdx.x, lane = t & 63, wv = t >> 6;
  int ntiles = (rows + 63) >> 6;
  float psum = 0.f, psq = 0.f;
  float bv = bias ? bias[lane] : 0.f;
  for (int tile = blockIdx.x; tile < ntiles; tile += gridDim.x) {
    int base = tile * 64;
    float acc[16];
#pragma unroll
    for (int j = 0; j < 16; j++) acc[j] = bv;
    for (int pass = 0; pass < (TWO ? 2 : 1); pass++) {
      const float* Xp = pass ? Xb : X;
      const float* Wp = pass ? Wb : Wm;
      __syncthreads();
#pragma unroll
      for (int m = 0; m < 16; m++) {
        int fl = m * 256 + t;
        int r = fl >> 6, c = fl & 63;
        int gr = base + r;
        float v = (gr < rows) ? Xp[gr * 64 + c] : 0.f;
        if (PRE) { v = pa[c] * v + pb[c]; if (PRELU) v = fmaxf(v, 0.f); }
        xs[fl] = v;
      }
      __syncthreads();
      float Wreg[64];
#pragma unroll
      for (int k = 0; k < 64; k++) Wreg[k] = Wp[lane * 64 + k];
#pragma unroll
      for (int j = 0; j < 16; j++) {
        int r = wv * 16 + j;
        const float4* xr = (const float4*)&xs[r * 64];
        float a = acc[j];
#pragma unroll
        for (int kk = 0; kk < 16; kk++) {
          float4 xv = xr[kk];
          a = fmaf(xv.x, Wreg[4 * kk + 0], a);
          a = fmaf(xv.y, Wreg[4 * kk + 1], a);
          a = fmaf(xv.z, Wreg[4 * kk + 2], a);
          a = fmaf(xv.w, Wreg[4 * kk + 3], a);
        }
        acc[j] = a;
      }
    }
#pragma unroll
    for (int j = 0; j < 16; j++) {
      int gr = base + wv * 16 + j;
      if (gr < rows) {
        float v = acc[j];
        if (PERG) v += perg[(gr % tabrows) * 64 + lane];
        Y[gr * 64 + lane] = v;
        if (STATS) { psum += v; psq += v * v; }
      }
    }
  }
  if (STATS) {
    __syncthreads();
    red[wv][lane] = psum; red2[wv][lane] = psq;
    __syncthreads();
    if (wv == 0) {
      float s = red[0][lane] + red[1][lane] + red[2][lane] + red[3][lane];
      float q = red2[0][lane] + red2[1][lane] + red2[2][lane] + red2[3][lane];
      atomicAdd(&stats[lane], s);
      atomicAdd(&stats[64 + lane], q);
    }
  }
}

// analytic S3: stats of u = a2*t2 + b2 + emb[b] from S2 (sum,sq) and per-batch sums Tb.
// Then Avec = a3*a2, e2[b] = a3*(b2+emb[b]) + b3.
__global__ __launch_bounds__(256) void kfinS3an(const float* __restrict__ S2,
                                                const float* __restrict__ a2, const float* __restrict__ b2,
                                                const float* __restrict__ emb, const float* __restrict__ Tb,
                                                const float* __restrict__ g, const float* __restrict__ bt,
                                                float* __restrict__ Avec, float* __restrict__ e2) {
  __shared__ float a3s[64], b3s[64];
  int t = threadIdx.x;
  if (t < 64) {
    float a2c = a2[t], b2c = b2[t];
    float se = 0.f, sct = 0.f, sc2 = 0.f;
    for (int b = 0; b < Bn; b++) {
      float cb = b2c + emb[b * 64 + t];
      se += cb;
      sct += cb * Tb[b * 64 + t];
      sc2 += cb * cb;
    }
    float sum_u = a2c * S2[t] + (float)Gn * se;
    float sq_u = a2c * a2c * S2[64 + t] + 2.f * a2c * sct + (float)Gn * sc2;
    float mean = sum_u / (float)Nn;
    float var = sq_u / (float)Nn - mean * mean;
    float sc = g[t] * rsqrtf(var + 1e-5f);
    float sh = bt[t] - mean * sc;
    a3s[t] = sc; b3s[t] = sh;
    Avec[t] = sc * a2c;
  }
  __syncthreads();
  for (int idx = t; idx < 2048; idx += 256) {
    int c = idx & 63;
    e2[idx] = a3s[c] * (b2[c] + emb[idx]) + b3s[c];
  }
}

// w1[i] = dot(a5*R2(bf16)+b5, indv_w1[i%G]) + indv_b1[i%G]
__global__ __launch_bounds__(256) void k13_kernel(const u16* __restrict__ R2, const float* __restrict__ a5,
                                                  const float* __restrict__ b5, const float* __restrict__ iw1,
                                                  const float* __restrict__ ib1, float* __restrict__ w1out,
                                                  int rows) {
  int t = blockIdx.x * 256 + threadIdx.x;
  int i = t >> 4, j = t & 15;
  if (i >= rows) return;
  int g = i % Gn;
  uint2 u = *(const uint2*)&R2[(size_t)i * 64 + j * 4];
  float rx = bflo(u.x), ry = bfhi(u.x), rz = bflo(u.y), rw = bfhi(u.y);
  float4 a = ((const float4*)a5)[j];
  float4 b = ((const float4*)b5)[j];
  float4 w = ((const float4*)iw1)[g * 16 + j];
  float p = (a.x * rx + b.x) * w.x + (a.y * ry + b.y) * w.y +
            (a.z * rz + b.z) * w.z + (a.w * rw + b.w) * w.w;
  for (int off = 8; off; off >>= 1) p += __shfl_xor(p, off, 64);
  if (j == 0) w1out[i] = p + ib1[g];
}

// init cgraw with bias
__global__ __launch_bounds__(256) void kinitcg(const float* __restrict__ cgb1, float* __restrict__ cgraw) {
  int idx = blockIdx.x * 256 + threadIdx.x;
  if (idx < Bn * 64) cgraw[idx] = cgb1[idx & 63];
}

// split-K GEMM: cgraw[b][col] += sum_{k in chunk} w1[b][k]*cgW1[col][k]
__global__ __launch_bounds__(256) void kcg1s(const float* __restrict__ w1, const float* __restrict__ cgW1,
                                             float* __restrict__ cgraw) {
  __shared__ float w1s[64 * 36];
  __shared__ float cgs[64 * 65];
  int t = threadIdx.x;
  int k0 = blockIdx.x * 64;
  int kmax = Gn - k0; if (kmax > 64) kmax = 64;
  for (int idx = t; idx < 2048; idx += 256) {
    int row = idx >> 6, k = idx & 63;
    w1s[k * 36 + row] = (k < kmax) ? w1[row * Gn + k0 + k] : 0.f;
  }
  for (int idx = t; idx < 4096; idx += 256) {
    int col = idx >> 6, k = idx & 63;
    cgs[k * 65 + col] = (k < kmax) ? cgW1[col * Gn + k0 + k] : 0.f;
  }
  __syncthreads();
  int col = t & 63, rg = t >> 6;
  float acc[8];
#pragma unroll
  for (int i = 0; i < 8; i++) acc[i] = 0.f;
  for (int k = 0; k < 64; k++) {
    float wk = cgs[k * 65 + col];
    const float* wr = &w1s[k * 36 + rg * 8];
    float4 r0 = *(const float4*)wr;
    float4 r1 = *(const float4*)(wr + 4);
    acc[0] = fmaf(r0.x, wk, acc[0]);
    acc[1] = fmaf(r0.y, wk, acc[1]);
    acc[2] = fmaf(r0.z, wk, acc[2]);
    acc[3] = fmaf(r0.w, wk, acc[3]);
    acc[4] = fmaf(r1.x, wk, acc[4]);
    acc[5] = fmaf(r1.y, wk, acc[5]);
    acc[6] = fmaf(r1.z, wk, acc[6]);
    acc[7] = fmaf(r1.w, wk, acc[7]);
  }
#pragma unroll
  for (int i = 0; i < 8; i++) atomicAdd(&cgraw[(rg * 8 + i) * 64 + col], acc[i]);
}

// single-block: cg2 = bn2(relu(bn1(cgraw)) @ W2^T + b2)   (BN over 32 rows)
__global__ __launch_bounds__(256) void kcg2(const float* __restrict__ cgraw, const float* __restrict__ g1,
                                            const float* __restrict__ bt1, const float* __restrict__ W2,
                                            const float* __restrict__ b2, const float* __restrict__ g2,
                                            const float* __restrict__ bt2, float* __restrict__ cg2out) {
  int t = threadIdx.x, c = t & 63, bg = t >> 6;
  __shared__ float hmid[2048], sred[4][64], qred[4][64], asc[64], bsh[64];
  float y[8];
  float ps = 0.f, pq = 0.f;
  for (int jb = 0; jb < 8; jb++) {
    int b = bg * 8 + jb;
    float v = cgraw[b * 64 + c];
    y[jb] = v; ps += v; pq += v * v;
  }
  sred[bg][c] = ps; qred[bg][c] = pq;
  __syncthreads();
  if (t < 64) {
    float s = sred[0][t] + sred[1][t] + sred[2][t] + sred[3][t];
    float q = qred[0][t] + qred[1][t] + qred[2][t] + qred[3][t];
    float mean = s * (1.f / 32.f), var = q * (1.f / 32.f) - mean * mean;
    float sc = g1[t] * rsqrtf(var + 1e-5f);
    asc[t] = sc; bsh[t] = bt1[t] - mean * sc;
  }
  __syncthreads();
  for (int jb = 0; jb < 8; jb++) { int b = bg * 8 + jb; hmid[b * 64 + c] = fmaxf(asc[c] * y[jb] + bsh[c], 0.f); }
  __syncthreads();
  ps = 0.f; pq = 0.f;
  for (int jb = 0; jb < 8; jb++) {
    int b = bg * 8 + jb;
    float a = b2[c];
    for (int k = 0; k < 64; k++) a += hmid[b * 64 + k] * W2[c * 64 + k];
    y[jb] = a; ps += a; pq += a * a;
  }
  sred[bg][c] = ps; qred[bg][c] = pq;
  __syncthreads();
  if (t < 64) {
    float s = sred[0][t] + sred[1][t] + sred[2][t] + sred[3][t];
    float q = qred[0][t] + qred[1][t] + qred[2][t] + qred[3][t];
    float mean = s * (1.f / 32.f), var = q * (1.f / 32.f) - mean * mean;
    float sc = g2[t] * rsqrtf(var + 1e-5f);
    asc[t] = sc; bsh[t] = bt2[t] - mean * sc;
  }
  __syncthreads();
  for (int jb = 0; jb < 8; jb++) { int b = bg * 8 + jb; cg2out[b * 64 + c] = asc[c] * y[jb] + bsh[c]; }
}

// single-block: emb = mlp3(pglob[pert_idx]) with BN over 32 rows
__global__ __launch_bounds__(256) void kemb(const float* __restrict__ m2, const float* __restrict__ aP2,
                                            const float* __restrict__ bP2, const int* __restrict__ pidx,
                                            const float* __restrict__ Wm, const float* __restrict__ bv,
                                            const float* __restrict__ gg, const float* __restrict__ btv,
                                            float* __restrict__ emb) {
  int t = threadIdx.x, c = t & 63, bg = t >> 6;
  __shared__ float xin[2048], hmid[2048], sred[4][64], qred[4][64], asc[64], bsh[64];
  for (int idx = t; idx < 2048; idx += 256) {
    int b = idx >> 6, cc = idx & 63;
    xin[idx] = aP2[cc] * m2[pidx[b] * 64 + cc] + bP2[cc];
  }
  __syncthreads();
  float y[8];
  float ps = 0.f, pq = 0.f;
  for (int jb = 0; jb < 8; jb++) {
    int b = bg * 8 + jb;
    float a = bv[c];
    for (int k = 0; k < 64; k++) a += xin[b * 64 + k] * Wm[c * 64 + k];
    y[jb] = a; ps += a; pq += a * a;
  }
  sred[bg][c] = ps; qred[bg][c] = pq;
  __syncthreads();
  if (t < 64) {
    float s = sred[0][t] + sred[1][t] + sred[2][t] + sred[3][t];
    float q = qred[0][t] + qred[1][t] + qred[2][t] + qred[3][t];
    float mean = s * (1.f / 32.f), var = q * (1.f / 32.f) - mean * mean;
    float sc = gg[t] * rsqrtf(var + 1e-5f);
    asc[t] = sc; bsh[t] = btv[t] - mean * sc;
  }
  __syncthreads();
  for (int jb = 0; jb < 8; jb++) { int b = bg * 8 + jb; hmid[b * 64 + c] = fmaxf(asc[c] * y[jb] + bsh[c], 0.f); }
  __syncthreads();
  ps = 0.f; pq = 0.f;
  for (int jb = 0; jb < 8; jb++) {
    int b = bg * 8 + jb;
    float a = bv[64 + c];
    for (int k = 0; k < 64; k++) a += hmid[b * 64 + k] * Wm[4096 + c * 64 + k];
    y[jb] = a; ps += a; pq += a * a;
  }
  sred[bg][c] = ps; qred[bg][c] = pq;
  __syncthreads();
  if (t < 64) {
    float s = sred[0][t] + sred[1][t] + sred[2][t] + sred[3][t];
    float q = qred[0][t] + qred[1][t] + qred[2][t] + qred[3][t];
    float mean = s * (1.f / 32.f), var = q * (1.f / 32.f) - mean * mean;
    float sc = gg[64 + t] * rsqrtf(var + 1e-5f);
    asc[t] = sc; bsh[t] = btv[64 + t] - mean * sc;
  }
  __syncthreads();
  for (int jb = 0; jb < 8; jb++) { int b = bg * 8 + jb; emb[b * 64 + c] = asc[c] * y[jb] + bsh[c]; }
}

// final: out[b][g] = w1*iw2[g][0] + dot(cg2[b], iw2[g][1:65]) + ib2[g] + x[b][g]
__global__ __launch_bounds__(256) void kfinal(const float* __restrict__ w1, const float* __restrict__ cg2,
                                              const float* __restrict__ iw2, const float* __restrict__ ib2,
                                              const float* __restrict__ x, float* __restrict__ out) {
  __shared__ float iws[64 * 65], cgs[2048];
  int t = threadIdx.x;
  int g0 = blockIdx.x * 64;
  for (int idx = t; idx < 64 * 65; idx += 256) {
    int gi = g0 * 65 + idx;
    iws[idx] = (gi < Gn * 65) ? iw2[gi] : 0.f;
  }
  for (int idx = t; idx < 2048; idx += 256) cgs[idx] = cg2[idx];
  __syncthreads();
  int gl = t & 63, bg = t >> 6;
  int g = g0 + gl;
  if (g >= Gn) return;
  float bias = ib2[g];
  for (int jb = 0; jb < 8; jb++) {
    int b = bg * 8 + jb;
    float acc = w1[b * Gn + g] * iws[gl * 65] + bias;
    for (int k = 0; k < 64; k++) acc += cgs[b * 64 + k] * iws[gl * 65 + 1 + k];
    out[b * Gn + g] = acc + x[b * Gn + g];
  }
}

extern "C" void kernel_launch(void* const* d_in, const int* in_sizes, int n_in,
                              void* d_out, int out_size, void* d_ws, size_t ws_size,
                              hipStream_t stream) {
  (void)in_sizes; (void)n_in; (void)out_size;
  if (ws_size < WS_FLOATS * sizeof(float)) return;

  const float* x        = (const float*)d_in[0];
  const int*   pert_idx = (const int*)d_in[1];
  const int*   ei_co    = (const int*)d_in[2];
  const float* w_co     = (const float*)d_in[3];
  const int*   ei_go    = (const int*)d_in[4];
  const float* w_go     = (const float*)d_in[5];
  const int*   ei_bg    = (const int*)d_in[6];
  const float* w_bg     = (const float*)d_in[7];
  const float* gene_tab = (const float*)d_in[8];
  const float* pos_tab  = (const float*)d_in[9];
  const float* go_tab   = (const float*)d_in[10];
  const float* bg_tab   = (const float*)d_in[11];
  const float* bn_g     = (const float*)d_in[12];
  const float* bn_b     = (const float*)d_in[13];
  const float* sg_W     = (const float*)d_in[14];
  const float* sg_b     = (const float*)d_in[15];
  const float* mlp_W    = (const float*)d_in[16];
  const float* mlp_b    = (const float*)d_in[17];
  const float* mlp_g    = (const float*)d_in[18];
  const float* mlp_bt   = (const float*)d_in[19];
  const float* rec_W1   = (const float*)d_in[20];
  const float* rec_b1   = (const float*)d_in[21];
  const float* rec_g1   = (const float*)d_in[22];
  const float* rec_bt1  = (const float*)d_in[23];
  const float* rec_W2   = (const float*)d_in[24];
  const float* rec_b2   = (const float*)d_in[25];
  const float* rec_g2   = (const float*)d_in[26];
  const float* rec_bt2  = (const float*)d_in[27];
  const float* indv_w1  = (const float*)d_in[28];
  const float* indv_b1  = (const float*)d_in[29];
  const float* cg_W1    = (const float*)d_in[30];
  const float* cg_b1    = (const float*)d_in[31];
  const float* cg_g1    = (const float*)d_in[32];
  const float* cg_bt1   = (const float*)d_in[33];
  const float* cg_W2    = (const float*)d_in[34];
  const float* cg_b2    = (const float*)d_in[35];
  const float* cg_g2    = (const float*)d_in[36];
  const float* cg_bt2   = (const float*)d_in[37];
  const float* indv_w2  = (const float*)d_in[38];
  const float* indv_b2  = (const float*)d_in[39];

  float* W = (float*)d_ws;
  float* buf0 = W + oBUF0;
  float* buf1 = W + oBUF1;

  // CSR scratch lives in buf1 (consumed before t1 writes buf1)
  int*    co_cnt    = (int*)(buf1);
  int*    sbsum     = (int*)(buf1 + 320128);
  float2* co_pack   = (float2*)(buf1 + 400000);
  int*    go_cnt    = (int*)(buf1 + 3700000);
  float2* go_pack   = (float2*)(buf1 + 3720000);
  int*    bg_cnt    = (int*)(buf1 + 4000000);
  float2* bg_pack   = (float2*)(buf1 + 4020000);
  int*    co_ticket = (int*)(buf1 + 4500000);
  int*    go_ticket = (int*)(buf1 + 6200000);
  int*    bg_ticket = (int*)(buf1 + 6400000);

  // --- phase 0: zero stats + Tb, renorm tables, fold small matrices ---
  kzero<<<8, 256, 0, stream>>>(W, 2048);
  kzero<<<8, 256, 0, stream>>>(W + oCGRAW, 2048);  // Tb (per-batch t2 col sums)
  krenorm<<<160, 256, 0, stream>>>(gene_tab, W + oRG, W + oSG, Gn);
  krenorm<<<160, 256, 0, stream>>>(pos_tab, W + oRP, nullptr, Gn);
  krenorm<<<160, 256, 0, stream>>>(go_tab, W + oRGO, nullptr, Pn);
  krenorm<<<160, 256, 0, stream>>>(bg_tab, W + oRBG, nullptr, Pn);
  kfin<<<1, 64, 0, stream>>>(W + oSG, bn_g, bn_b, W + oAG, W + oBG, 64, 1.f / Gn);
  ksmallmat<<<1, 256, 0, stream>>>(mlp_W + 8192, sg_W, 0.2f, mlp_b + 128, sg_b, nullptr, 0.2f, W + oM, W + oCvec);
  ksmallmat<<<1, 256, 0, stream>>>(mlp_W, sg_W + 4096, 1.f, nullptr, nullptr, nullptr, 0.f, W + oM1, nullptr);
  ksmallmat<<<1, 256, 0, stream>>>(mlp_W, sg_W + 8192, 1.f, mlp_b, sg_b + 64, sg_b + 128, 1.f, W + oM2, W + oCcP);
  gemm64k<false, true, true, false, false><<<79, 256, 0, stream>>>(
      W + oRG, nullptr, mlp_W + 8192, nullptr, W + oCvec, W + oAG, W + oBG, nullptr, 0, W + oQ, nullptr, Gn);

  // --- co graph: ticket CSR build + gather (bf16 out) ---
  kzero<<<(160001 + 255) / 256, 256, 0, stream>>>((float*)co_cnt, 160001);
  khist<<<(ECO + 255) / 256, 256, 0, stream>>>(ei_co + ECO, co_cnt, co_ticket, ECO);
  kscan1<<<157, 256, 0, stream>>>(co_cnt, sbsum, Nn);
  kscan2<<<1, 256, 0, stream>>>(sbsum, 157, co_cnt + Nn);
  kscan3<<<157, 256, 0, stream>>>(co_cnt, sbsum, Nn);
  kfillt<<<(ECO + 255) / 256, 256, 0, stream>>>(ei_co, ei_co + ECO, w_co, co_cnt, co_ticket, co_pack, ECO);
  kdinvrow<<<(Nn + 255) / 256, 256, 0, stream>>>(co_cnt, co_pack, W + oDEG, Nn);
  kgather<true><<<2048, 256, 0, stream>>>(co_cnt, co_pack, W + oDEG, W + oRP, nullptr, (u16*)buf0, Nn);

  // --- go graph ---
  kzero<<<(5001 + 255) / 256, 256, 0, stream>>>((float*)go_cnt, 5001);
  khist<<<(EGG + 255) / 256, 256, 0, stream>>>(ei_go + EGG, go_cnt, go_ticket, EGG);
  kscan1<<<5, 256, 0, stream>>>(go_cnt, sbsum, Pn);
  kscan2<<<1, 256, 0, stream>>>(sbsum, 5, go_cnt + Pn);
  kscan3<<<5, 256, 0, stream>>>(go_cnt, sbsum, Pn);
  kfillt<<<(EGG + 255) / 256, 256, 0, stream>>>(ei_go, ei_go + EGG, w_go, go_cnt, go_ticket, go_pack, EGG);
  kdinvrow<<<(Pn + 255) / 256, 256, 0, stream>>>(go_cnt, go_pack, W + oDGO, Pn);
  kgather<false><<<512, 256, 0, stream>>>(go_cnt, go_pack, W + oDGO, W + oRGO, W + oAGO, nullptr, Pn);

  // --- bg graph ---
  kzero<<<(5001 + 255) / 256, 256, 0, stream>>>((float*)bg_cnt, 5001);
  khist<<<(EGG + 255) / 256, 256, 0, stream>>>(ei_bg + EGG, bg_cnt, bg_ticket, EGG);
  kscan1<<<5, 256, 0, stream>>>(bg_cnt, sbsum, Pn);
  kscan2<<<1, 256, 0, stream>>>(sbsum, 5, bg_cnt + Pn);
  kscan3<<<5, 256, 0, stream>>>(bg_cnt, sbsum, Pn);
  kfillt<<<(EGG + 255) / 256, 256, 0, stream>>>(ei_bg, ei_bg + EGG, w_bg, bg_cnt, bg_ticket, bg_pack, EGG);
  kdinvrow<<<(Pn + 255) / 256, 256, 0, stream>>>(bg_cnt, bg_pack, W + oDBG, Pn);
  kgather<false><<<512, 256, 0, stream>>>(bg_cnt, bg_pack, W + oDBG, W + oRBG, W + oABG, nullptr, Pn);

  // --- pert path (Pn rows, fp32) ---
  gemm64k<true, false, false, false, true><<<79, 256, 0, stream>>>(
      W + oAGO, W + oABG, W + oM1, W + oM2, W + oCcP, nullptr, nullptr, nullptr, 0, W + oM1B, W + oSP1, Pn);
  kfin<<<1, 64, 0, stream>>>(W + oSP1, mlp_g, mlp_bt, W + oAP1, W + oBP1, 64, 1.f / Pn);
  gemm64k<false, true, true, false, true><<<79, 256, 0, stream>>>(
      W + oM1B, nullptr, mlp_W + 4096, nullptr, mlp_b + 64, W + oAP1, W + oBP1, nullptr, 0, W + oM2B, W + oSP2, Pn);
  kfin<<<1, 64, 0, stream>>>(W + oSP2, mlp_g + 64, mlp_bt + 64, W + oAP2, W + oBP2, 64, 1.f / Pn);
  kemb<<<1, 256, 0, stream>>>(W + oM2B, W + oAP2, W + oBP2, pert_idx,
                              mlp_W + 16384, mlp_b + 256, mlp_g + 256, mlp_bt + 256, W + oEMB);

  // --- main N pipeline (bf16 intermediates) ---
  // t1 = agg@M^T + Q[g]; stats S1
  gemm_big<false, false, true, false><<<512, 256, 0, stream>>>(
      (const u16*)buf0, W + oM, W + oZERO, nullptr, nullptr, W + oQ, (u16*)buf1, 64, W + oS1, 64, nullptr);
  kfin<<<1, 64, 0, stream>>>(W + oS1, mlp_g + 128, mlp_bt + 128, W + oA1, W + oB1, 64, 1.f / Nn);
  // t2 = relu(a1*t1+b1)@W11^T + b11; stats S2 + per-batch col sums Tb
  gemm_big<true, false, false, true><<<512, 256, 0, stream>>>(
      (const u16*)buf1, mlp_W + 12288, mlp_b + 192, W + oA1, W + oB1, nullptr, (u16*)buf0, 64, W + oS2, 64,
      W + oCGRAW);
  kfin<<<1, 64, 0, stream>>>(W + oS2, mlp_g + 192, mlp_bt + 192, W + oA2, W + oB2, 64, 1.f / Nn);
  // analytic S3 -> Avec, e2 (replaces the full k7 pass)
  kfinS3an<<<1, 256, 0, stream>>>(W + oS2, W + oA2, W + oB2, W + oEMB, W + oCGRAW,
                                  bn_g + 64, bn_b + 64, W + oAvec, W + oE2);
  // r1 merged (both halves, t2 read once): r1 bf16 pitch 128; stats S4 (128)
  gemm_r1<<<512, 256, 0, stream>>>(
      (const u16*)buf0, rec_W1, rec_b1, W + oAvec, W + oE2, (u16*)buf1, W + oS4);
  kfin<<<2, 64, 0, stream>>>(W + oS4, rec_g1, rec_bt1, W + oA4, W + oB4, 128, 1.f / Nn);
  // r2 = relu(a4*r1+b4)@W2^T + b2; stats S5; bf16 out
  gemm_k11<<<512, 256, 0, stream>>>((const u16*)buf1, rec_W2, rec_b2, W + oA4, W + oB4, (u16*)buf0, W + oS5);
  kfin<<<1, 64, 0, stream>>>(W + oS5, rec_g2, rec_bt2, W + oA5, W + oB5, 64, 1.f / Nn);
  k13_kernel<<<(Nn * 16 + 255) / 256, 256, 0, stream>>>((const u16*)buf0, W + oA5, W + oB5, indv_w1, indv_b1,
                                                        W + oW1, Nn);
  // cross-gene state (cgraw reuses oCGRAW — Tb is dead after kfinS3an)
  kinitcg<<<8, 256, 0, stream>>>(cg_b1, W + oCGRAW);
  kcg1s<<<(Gn + 63) / 64, 256, 0, stream>>>(W + oW1, cg_W1, W + oCGRAW);
  kcg2<<<1, 256, 0, stream>>>(W + oCGRAW, cg_g1, cg_bt1, cg_W2, cg_b2, cg_g2, cg_bt2, W + oCG2);
  kfinal<<<(Gn + 63) / 64, 256, 0, stream>>>(W + oW1, W + oCG2, indv_w2, indv_b2, x, (float*)d_out);
}